// Round 20
// baseline (397.338 us; speedup 1.0000x reference)
//
#include <hip/hip_runtime.h>
#include <hip/hip_bf16.h>
#include <math.h>

#define H_DIM   2048
#define NH      16
#define NKV     4
#define HD      128
#define NE      16
#define TOPK    4
#define DFF     1024
#define NG      4
#define SEQ     1024
#define QKV_N   3072          // (NH + 2*NKV)*HD
#define EPS_RMS 1e-6f
#define THETA   1000000.0f

typedef __attribute__((ext_vector_type(8))) short bf16x8;
typedef __attribute__((ext_vector_type(4))) short s16x4;
typedef __attribute__((ext_vector_type(4))) float f32x4;

__device__ inline unsigned short f2bf(float x) {
    unsigned u = __builtin_bit_cast(unsigned, x);
    unsigned r = (u + 0x7FFFu + ((u >> 16) & 1u)) >> 16;
    return (unsigned short)r;
}

// pack two floats -> u32 of 2 bf16 (lo, hi); lowers to v_cvt_pk_bf16_f32
__device__ inline unsigned pk2bf(float lo, float hi) {
    __hip_bfloat162 h = __float22bfloat162_rn(float2{lo, hi});
    unsigned r;
    __builtin_memcpy(&r, &h, 4);
    return r;
}

// ---------------------------------------------------------------- weight transpose + bf16 convert (small weights only)
__global__ __launch_bounds__(256) void w2bfT(const float* __restrict__ in,
                                             unsigned short* __restrict__ out,
                                             int K, int N) {
    const float* src = in + (size_t)blockIdx.z * K * N;
    unsigned short* dst = out + (size_t)blockIdx.z * K * N;
    int n0 = blockIdx.x * 64, k0 = blockIdx.y * 64;
    __shared__ unsigned short tile[64][66];
    int tid = threadIdx.x, c = tid & 63, r4 = tid >> 6;
    #pragma unroll
    for (int rep = 0; rep < 16; rep++) {
        int r = rep * 4 + r4;
        tile[r][c] = f2bf(src[(size_t)(k0 + r) * N + n0 + c]);
    }
    __syncthreads();
    #pragma unroll
    for (int rep = 0; rep < 16; rep++) {
        int r = rep * 4 + r4;
        dst[(size_t)(n0 + r) * K + k0 + c] = tile[c][r];
    }
}

// ---------------------------------------------------------------- RMSNorm (f32 in, optional f32 + bf16 out)
__global__ __launch_bounds__(256) void rmsnorm_dual(const float* __restrict__ in,
                                                    const float* __restrict__ w,
                                                    float* __restrict__ outf,
                                                    unsigned short* __restrict__ outb) {
    int t = blockIdx.x;
    const float* xt = in + (size_t)t * H_DIM;
    float ss = 0.f;
    for (int d = threadIdx.x * 4; d < H_DIM; d += 1024) {
        float4 v = *reinterpret_cast<const float4*>(xt + d);
        ss += v.x * v.x + v.y * v.y + v.z * v.z + v.w * v.w;
    }
    for (int off = 1; off < 64; off <<= 1) ss += __shfl_xor(ss, off);
    __shared__ float red[4];
    __shared__ float srms;
    if ((threadIdx.x & 63) == 0) red[threadIdx.x >> 6] = ss;
    __syncthreads();
    if (threadIdx.x == 0)
        srms = rsqrtf((red[0] + red[1] + red[2] + red[3]) * (1.f / H_DIM) + EPS_RMS);
    __syncthreads();
    float r = srms;
    for (int d = threadIdx.x * 4; d < H_DIM; d += 1024) {
        float4 v  = *reinterpret_cast<const float4*>(xt + d);
        float4 wv = *reinterpret_cast<const float4*>(w + d);
        float4 ov;
        ov.x = v.x * r * wv.x; ov.y = v.y * r * wv.y;
        ov.z = v.z * r * wv.z; ov.w = v.w * r * wv.w;
        if (outf) *reinterpret_cast<float4*>(outf + (size_t)t * H_DIM + d) = ov;
        if (outb) {
            s16x4 bv = (s16x4){(short)f2bf(ov.x), (short)f2bf(ov.y),
                               (short)f2bf(ov.z), (short)f2bf(ov.w)};
            *reinterpret_cast<s16x4*>(outb + (size_t)t * H_DIM + d) = bv;
        }
    }
}

// ---------------------------------------------------------------- qkv GEMM (Bt bf16) fused RoPE + pack
// BM=64 (2 waves x 32 rows), BN=128 (=1 head), BK=64. 128 threads. grid (24, SEQ/64)
__global__ __launch_bounds__(128) void gemm_qkv_rope(const unsigned short* __restrict__ A,
                                                     const unsigned short* __restrict__ Bt,
                                                     const int* __restrict__ positions,
                                                     unsigned short* __restrict__ Qb,
                                                     unsigned short* __restrict__ Kb,
                                                     unsigned short* __restrict__ Vt) {
    __shared__ unsigned short As[8][66][8];    // [kg][row][k&7], +2 row pad
    __shared__ unsigned short Bs[8][130][8];
    int xb = blockIdx.x;                       // 0..23: 0-15 Q heads, 16-19 K, 20-23 V
    int row0 = blockIdx.y * 64, col0 = xb * 128;
    int t = threadIdx.x;
    int w = t >> 6, lane = t & 63, lo = lane & 15, g = lane >> 4;
    int wr = w * 32;
    f32x4 acc[2][8];
    #pragma unroll
    for (int mi = 0; mi < 2; mi++)
        #pragma unroll
        for (int ni = 0; ni < 8; ni++) acc[mi][ni] = (f32x4){0.f, 0.f, 0.f, 0.f};
    int arow8 = t >> 3, ac = t & 7;            // 16 rows per pass, 8 lanes/row
    size_t aoff[4], boff[8];
    #pragma unroll
    for (int rep = 0; rep < 4; rep++)
        aoff[rep] = (size_t)(row0 + rep * 16 + arow8) * H_DIM + ac * 8;
    #pragma unroll
    for (int rep = 0; rep < 8; rep++)
        boff[rep] = (size_t)(col0 + rep * 16 + arow8) * H_DIM + ac * 8;
    bf16x8 aR[4], bR[8];
    #pragma unroll
    for (int rep = 0; rep < 4; rep++) aR[rep] = *(const bf16x8*)(A + aoff[rep]);
    #pragma unroll
    for (int rep = 0; rep < 8; rep++) bR[rep] = *(const bf16x8*)(Bt + boff[rep]);
    for (int k0 = 0; k0 < H_DIM; k0 += 64) {
        #pragma unroll
        for (int rep = 0; rep < 4; rep++)
            *(bf16x8*)As[ac][rep * 16 + arow8] = aR[rep];
        #pragma unroll
        for (int rep = 0; rep < 8; rep++)
            *(bf16x8*)Bs[ac][rep * 16 + arow8] = bR[rep];
        int kn = k0 + 64;
        if (kn < H_DIM) {
            #pragma unroll
            for (int rep = 0; rep < 4; rep++) aR[rep] = *(const bf16x8*)(A + aoff[rep] + kn);
            #pragma unroll
            for (int rep = 0; rep < 8; rep++) bR[rep] = *(const bf16x8*)(Bt + boff[rep] + kn);
        }
        __syncthreads();
        #pragma unroll
        for (int kh = 0; kh < 2; kh++) {
            bf16x8 af[2], bfr[8];
            #pragma unroll
            for (int mi = 0; mi < 2; mi++) af[mi] = *(const bf16x8*)As[kh * 4 + g][wr + mi * 16 + lo];
            #pragma unroll
            for (int ni = 0; ni < 8; ni++) bfr[ni] = *(const bf16x8*)Bs[kh * 4 + g][ni * 16 + lo];
            #pragma unroll
            for (int mi = 0; mi < 2; mi++)
                #pragma unroll
                for (int ni = 0; ni < 8; ni++)
                    acc[mi][ni] = __builtin_amdgcn_mfma_f32_16x16x32_bf16(af[mi], bfr[ni], acc[mi][ni], 0, 0, 0);
        }
        __syncthreads();
    }
    if (xb < NH + NKV) {
        bool isQ = (xb < NH);
        unsigned short* dst = isQ ? (Qb + (size_t)xb * SEQ * HD)
                                  : (Kb + (size_t)(xb - NH) * SEQ * HD);
        float qs = isQ ? 0.08838834764831845f : 1.0f;
        float invf[4];
        #pragma unroll
        for (int ni = 0; ni < 4; ni++)
            invf[ni] = __powf(THETA, -(float)(ni * 16 + lo) * (1.0f / 64.0f));
        #pragma unroll
        for (int mi = 0; mi < 2; mi++)
            #pragma unroll
            for (int r = 0; r < 4; r++) {
                int tok = row0 + wr + mi * 16 + g * 4 + r;
                float pos = (float)positions[tok];
                #pragma unroll
                for (int ni = 0; ni < 4; ni++) {
                    float s, c;
                    __sincosf(pos * invf[ni], &s, &c);
                    float x1 = acc[mi][ni][r], x2 = acc[mi][ni + 4][r];
                    int d = ni * 16 + lo;
                    dst[(size_t)tok * HD + d]      = f2bf((x1 * c - x2 * s) * qs);
                    dst[(size_t)tok * HD + d + 64] = f2bf((x2 * c + x1 * s) * qs);
                }
            }
    } else {
        int kvh = xb - (NH + NKV);
        #pragma unroll
        for (int mi = 0; mi < 2; mi++)
            #pragma unroll
            for (int ni = 0; ni < 8; ni++) {
                int tok0 = row0 + wr + mi * 16 + g * 4;
                int d = ni * 16 + lo;
                ushort4 v4;
                v4.x = f2bf(acc[mi][ni][0]);
                v4.y = f2bf(acc[mi][ni][1]);
                v4.z = f2bf(acc[mi][ni][2]);
                v4.w = f2bf(acc[mi][ni][3]);
                *reinterpret_cast<ushort4*>(Vt + ((size_t)kvh * HD + d) * SEQ + tok0) = v4;
            }
    }
}

// ---------------------------------------------------------------- o-proj GEMM (Bt bf16) + residual
// BM=128, BN=64, BK=64. 256 threads. grid (N/64, M/128).
__global__ __launch_bounds__(256) void gemm_bf16(const unsigned short* __restrict__ A,
                                                 const unsigned short* __restrict__ Bt,
                                                 float* __restrict__ C,
                                                 float* __restrict__ C2,
                                                 const float* __restrict__ R,
                                                 int M, int N, int K) {
    __shared__ unsigned short As[8][130][8];
    __shared__ unsigned short Bs[8][66][8];
    int row0 = blockIdx.y * 128, col0 = blockIdx.x * 64;
    int t = threadIdx.x;
    int w = t >> 6, lane = t & 63, lo = lane & 15, g = lane >> 4;
    int wr = (w >> 1) * 64, wc = (w & 1) * 32;
    f32x4 acc[4][2];
    #pragma unroll
    for (int mi = 0; mi < 4; mi++)
        #pragma unroll
        for (int ni = 0; ni < 2; ni++) acc[mi][ni] = (f32x4){0.f, 0.f, 0.f, 0.f};
    int arow8 = t >> 3, ac = t & 7;
    size_t aoff[4], boff[2];
    #pragma unroll
    for (int rep = 0; rep < 4; rep++)
        aoff[rep] = (size_t)(row0 + rep * 32 + arow8) * K + ac * 8;
    #pragma unroll
    for (int rep = 0; rep < 2; rep++)
        boff[rep] = (size_t)(col0 + rep * 32 + arow8) * K + ac * 8;
    bf16x8 aR[4], bR[2];
    #pragma unroll
    for (int rep = 0; rep < 4; rep++) aR[rep] = *(const bf16x8*)(A + aoff[rep]);
    #pragma unroll
    for (int rep = 0; rep < 2; rep++) bR[rep] = *(const bf16x8*)(Bt + boff[rep]);
    for (int k0 = 0; k0 < K; k0 += 64) {
        #pragma unroll
        for (int rep = 0; rep < 4; rep++)
            *(bf16x8*)As[ac][rep * 32 + arow8] = aR[rep];
        #pragma unroll
        for (int rep = 0; rep < 2; rep++)
            *(bf16x8*)Bs[ac][rep * 32 + arow8] = bR[rep];
        int kn = k0 + 64;
        if (kn < K) {
            #pragma unroll
            for (int rep = 0; rep < 4; rep++) aR[rep] = *(const bf16x8*)(A + aoff[rep] + kn);
            #pragma unroll
            for (int rep = 0; rep < 2; rep++) bR[rep] = *(const bf16x8*)(Bt + boff[rep] + kn);
        }
        __syncthreads();
        #pragma unroll
        for (int kh = 0; kh < 2; kh++) {
            bf16x8 af[4], bfr[2];
            #pragma unroll
            for (int mi = 0; mi < 4; mi++) af[mi] = *(const bf16x8*)As[kh * 4 + g][wr + mi * 16 + lo];
            #pragma unroll
            for (int ni = 0; ni < 2; ni++) bfr[ni] = *(const bf16x8*)Bs[kh * 4 + g][wc + ni * 16 + lo];
            #pragma unroll
            for (int mi = 0; mi < 4; mi++)
                #pragma unroll
                for (int ni = 0; ni < 2; ni++)
                    acc[mi][ni] = __builtin_amdgcn_mfma_f32_16x16x32_bf16(af[mi], bfr[ni], acc[mi][ni], 0, 0, 0);
        }
        __syncthreads();
    }
    #pragma unroll
    for (int mi = 0; mi < 4; mi++)
        #pragma unroll
        for (int ni = 0; ni < 2; ni++)
            #pragma unroll
            for (int r = 0; r < 4; r++) {
                int row = row0 + wr + mi * 16 + g * 4 + r;
                int col = col0 + wc + ni * 16 + lo;
                size_t idx = (size_t)row * N + col;
                float v = acc[mi][ni][r];
                if (R)  v += R[idx];
                C[idx] = v;
                if (C2) C2[idx] = v;
            }
}

// ---------------------------------------------------------------- flash attention, 4 waves / block:
// (mirrored q-pair) x (kv-half split) -> 8 waves/CU, halved critical path.
__global__ __launch_bounds__(256) void attn_mfma(const unsigned short* __restrict__ Qb,
                                                 const unsigned short* __restrict__ Kb,
                                                 const unsigned short* __restrict__ Vt,
                                                 unsigned short* __restrict__ ob) {
    int bx = blockIdx.x;
    int h  = blockIdx.y;
    int kvh = h >> 2;
    int tid = threadIdx.x;
    int wid = tid >> 6;
    int qsel = wid >> 1, khalf = wid & 1;
    int qt = qsel ? (SEQ / 16 - 1 - bx) : bx;
    int q0 = qt * 16;
    int l = tid & 63;
    int lo = l & 15, g = l >> 4;

    __shared__ alignas(16) unsigned short pbuf[4][16][40];
    __shared__ float obuf[2][16][128];
    __shared__ float mbuf[2][16], lbuf[2][16];

    bf16x8 qf[4];
    const unsigned short* qp = Qb + ((size_t)h * SEQ + q0 + lo) * HD + g * 8;
    #pragma unroll
    for (int ks = 0; ks < 4; ks++)
        qf[ks] = *(const bf16x8*)(qp + ks * 32);

    f32x4 accO[8];
    #pragma unroll
    for (int nd = 0; nd < 8; nd++) accO[nd] = (f32x4){0.f, 0.f, 0.f, 0.f};
    float mrun[4], lrun[4];
    #pragma unroll
    for (int r = 0; r < 4; r++) { mrun[r] = -INFINITY; lrun[r] = 0.f; }

    int nc = (q0 + 16 + 31) / 32;
    int ncH = (nc + 1) >> 1;
    int cbeg = khalf ? ncH : 0;
    int cend = khalf ? nc : ncH;
    for (int ch = cbeg; ch < cend; ch++) {
        int kv0 = ch * 32;
        f32x4 accS[2];
        accS[0] = (f32x4){0.f, 0.f, 0.f, 0.f};
        accS[1] = (f32x4){0.f, 0.f, 0.f, 0.f};
        const unsigned short* kp = Kb + ((size_t)kvh * SEQ + kv0 + lo) * HD + g * 8;
        #pragma unroll
        for (int n = 0; n < 2; n++) {
            const unsigned short* kpn = kp + (size_t)n * 16 * HD;
            #pragma unroll
            for (int ks = 0; ks < 4; ks++) {
                bf16x8 kf = *(const bf16x8*)(kpn + ks * 32);
                accS[n] = __builtin_amdgcn_mfma_f32_16x16x32_bf16(qf[ks], kf, accS[n], 0, 0, 0);
            }
        }
        if (ch == nc - 1) {
            #pragma unroll
            for (int n = 0; n < 2; n++)
                #pragma unroll
                for (int r = 0; r < 4; r++) {
                    int kv = kv0 + n * 16 + lo;
                    int q  = q0 + g * 4 + r;
                    if (kv > q) accS[n][r] = -1e30f;
                }
        }
        float mt[4], fac[4];
        #pragma unroll
        for (int r = 0; r < 4; r++) {
            float m = fmaxf(accS[0][r], accS[1][r]);
            #pragma unroll
            for (int off = 1; off < 16; off <<= 1) m = fmaxf(m, __shfl_xor(m, off));
            mt[r] = fmaxf(mrun[r], m);
            fac[r] = __expf(mrun[r] - mt[r]);
        }
        float psum[4] = {0.f, 0.f, 0.f, 0.f};
        #pragma unroll
        for (int n = 0; n < 2; n++)
            #pragma unroll
            for (int r = 0; r < 4; r++) {
                float p = __expf(accS[n][r] - mt[r]);
                psum[r] += p;
                pbuf[wid][g * 4 + r][n * 16 + lo] = f2bf(p);
            }
        #pragma unroll
        for (int r = 0; r < 4; r++) {
            float s = psum[r];
            #pragma unroll
            for (int off = 1; off < 16; off <<= 1) s += __shfl_xor(s, off);
            lrun[r] = lrun[r] * fac[r] + s;
            mrun[r] = mt[r];
        }
        #pragma unroll
        for (int nd = 0; nd < 8; nd++)
            #pragma unroll
            for (int r = 0; r < 4; r++) accO[nd][r] *= fac[r];
        __builtin_amdgcn_sched_barrier(0);
        bf16x8 pf = *(const bf16x8*)(&pbuf[wid][lo][g * 8]);
        const unsigned short* vp = Vt + ((size_t)kvh * HD + lo) * SEQ + kv0 + g * 8;
        #pragma unroll
        for (int nd = 0; nd < 8; nd++) {
            bf16x8 vf = *(const bf16x8*)(vp + (size_t)nd * 16 * SEQ);
            accO[nd] = __builtin_amdgcn_mfma_f32_16x16x32_bf16(pf, vf, accO[nd], 0, 0, 0);
        }
        __builtin_amdgcn_sched_barrier(0);
    }
    // kv-half merge: wave khalf=1 publishes partials; khalf=0 merges + writes out
    if (khalf) {
        #pragma unroll
        for (int r = 0; r < 4; r++) {
            if (lo == 0) {
                mbuf[qsel][g * 4 + r] = mrun[r];
                lbuf[qsel][g * 4 + r] = lrun[r];
            }
            #pragma unroll
            for (int nd = 0; nd < 8; nd++)
                obuf[qsel][g * 4 + r][nd * 16 + lo] = accO[nd][r];
        }
    }
    __syncthreads();
    if (!khalf) {
        #pragma unroll
        for (int r = 0; r < 4; r++) {
            int row = g * 4 + r;
            float m1 = mbuf[qsel][row], l1 = lbuf[qsel][row];
            float m0 = mrun[r], l0 = lrun[r];
            float m = fmaxf(m0, m1);
            float f0 = (l0 > 0.f) ? __expf(m0 - m) : 0.f;
            float f1 = (l1 > 0.f) ? __expf(m1 - m) : 0.f;
            float linv = 1.f / (l0 * f0 + l1 * f1);
            #pragma unroll
            for (int nd = 0; nd < 8; nd++) {
                float v = (accO[nd][r] * f0 + obuf[qsel][row][nd * 16 + lo] * f1) * linv;
                ob[(size_t)(q0 + row) * H_DIM + h * HD + nd * 16 + lo] = f2bf(v);
            }
        }
    }
}

// ---------------------------------------------------------------- router (wave-parallel: 4 waves x 4 experts)
__global__ __launch_bounds__(256) void router_kernel(const float* __restrict__ x,
                                                     const float* __restrict__ gate_w,
                                                     const float* __restrict__ gate_bias,
                                                     int* __restrict__ toklist,
                                                     float* __restrict__ tokw,
                                                     int* __restrict__ cnt) {
    int t = blockIdx.x;
    const float* xt = x + (size_t)t * H_DIM;
    __shared__ float logits[NE];
    int wid = threadIdx.x >> 6, lane = threadIdx.x & 63;
    #pragma unroll
    for (int i = 0; i < 4; i++) {
        int e = wid * 4 + i;
        const float* gw = gate_w + (size_t)e * H_DIM;
        float p = 0.f;
        for (int d = lane * 4; d < H_DIM; d += 256) {
            float4 xv = *reinterpret_cast<const float4*>(xt + d);
            float4 wv = *reinterpret_cast<const float4*>(gw + d);
            p += xv.x * wv.x + xv.y * wv.y + xv.z * wv.z + xv.w * wv.w;
        }
        #pragma unroll
        for (int off = 1; off < 64; off <<= 1) p += __shfl_xor(p, off);
        if (lane == 0) logits[e] = p;
    }
    __syncthreads();
    if (threadIdx.x == 0) {
        float sig[NE], sb[NE];
        for (int e = 0; e < NE; e++) {
            sig[e] = 1.f / (1.f + expf(-logits[e]));
            sb[e] = sig[e] + gate_bias[e];
        }
        float gs[NG];
        for (int g = 0; g < NG; g++) {
            float m1 = -1e30f, m2 = -1e30f;
            for (int i = 0; i < 4; i++) {
                float v = sb[g * 4 + i];
                if (v > m1) { m2 = m1; m1 = v; } else if (v > m2) m2 = v;
            }
            gs[g] = m1 + m2;
        }
        int g1 = 0;
        for (int g = 1; g < NG; g++) if (gs[g] > gs[g1]) g1 = g;
        int g2 = -1;
        for (int g = 0; g < NG; g++) {
            if (g == g1) continue;
            if (g2 < 0 || gs[g] > gs[g2]) g2 = g;
        }
        bool allowed[NE], used[NE];
        for (int e = 0; e < NE; e++) { int g = e >> 2; allowed[e] = (g == g1 || g == g2); used[e] = false; }
        int sel[TOPK]; float wsel[TOPK]; float wsum = 0.f;
        for (int k = 0; k < TOPK; k++) {
            int best = -1; float bv = -1e30f;
            for (int e = 0; e < NE; e++) {
                if (!allowed[e] || used[e]) continue;
                if (best < 0 || sb[e] > bv) { best = e; bv = sb[e]; }
            }
            used[best] = true; sel[k] = best; wsel[k] = sig[best]; wsum += sig[best];
        }
        float invs = 1.f / (wsum + 1e-20f);
        for (int k = 0; k < TOPK; k++) {
            int e = sel[k];
            int slot = atomicAdd(&cnt[e], 1);
            toklist[e * SEQ + slot] = t;
            tokw[e * SEQ + slot] = wsel[k] * invs;
        }
    }
}

__global__ void prefix_kernel(const int* __restrict__ cnt, int* __restrict__ base) {
    if (threadIdx.x == 0) {
        int s = 0;
        for (int e = 0; e < NE; e++) { base[e] = s; s += cnt[e]; }
    }
}

// ---------------------------------------------------------------- MoE GEMM1 (split-K x2): f32 partials
// BM=256, BN=32 (G and U each), BK=64, depth-1 prefetch, K split across 2 blocks.
// grid (DFF/32, (SEQ/256)*2, NE) -> 1024 active blocks (3/CU by LDS).
__global__ __launch_bounds__(256, 2) void moe_gemm1_mfma(const unsigned short* __restrict__ xb,
                                                         const float* __restrict__ gup,
                                                         const int* __restrict__ toklist,
                                                         const int* __restrict__ cnt,
                                                         const int* __restrict__ base,
                                                         float* __restrict__ pG,
                                                         float* __restrict__ pU) {
    int e = blockIdx.z;
    int ce = cnt[e];
    int yb = blockIdx.y;
    int khalf = yb & 1;
    int t0 = (yb >> 1) * 256;
    if (t0 >= ce) return;
    int f0 = blockIdx.x * 32;
    const int KB = H_DIM / 2;                  // 1024 per k-half
    int kbeg = khalf * KB;
    __shared__ unsigned short As[8][258][8];   // [kg][row][k&7]
    __shared__ unsigned short BsG[8][33][8];
    __shared__ unsigned short BsU[8][33][8];
    __shared__ int toks[256];
    int t = threadIdx.x;
    { int s = t0 + t; toks[t] = toklist[e * SEQ + (s < ce ? s : 0)]; }
    __syncthreads();
    int w = t >> 6, lane = t & 63, lo = lane & 15, g = lane >> 4;
    int wrb = w * 64;
    f32x4 accG[4][2], accU[4][2];
    #pragma unroll
    for (int mi = 0; mi < 4; mi++)
        #pragma unroll
        for (int ni = 0; ni < 2; ni++) {
            accG[mi][ni] = (f32x4){0.f, 0.f, 0.f, 0.f};
            accU[mi][ni] = (f32x4){0.f, 0.f, 0.f, 0.f};
        }
    // A staging: 8 lanes per row (128B line), 32 rows per pass, 8 passes
    int arow8 = t >> 3, ac = t & 7;
    size_t abase[8];
    #pragma unroll
    for (int rep = 0; rep < 8; rep++)
        abase[rep] = (size_t)toks[rep * 32 + arow8] * H_DIM + ac * 8;
    // B staging: t<128 -> G, t>=128 -> U; rows {2rp,2rp+1,2rp+32,2rp+33}, cols nq*4..+3
    int half = t >> 7, tt = t & 127;
    int rp = tt >> 3, nq = tt & 7;
    int kgB = rp >> 2, wq = (rp & 3) * 2;
    unsigned short (*Bsel)[33][8] = half ? BsU : BsG;
    const float* W = gup + (size_t)e * H_DIM * (2 * DFF);
    const float* pB0 = W + (size_t)(2 * rp) * (2 * DFF) + half * DFF + f0 + nq * 4;
    // prologue (k = kbeg)
    bf16x8 aR[8];
    #pragma unroll
    for (int rep = 0; rep < 8; rep++) aR[rep] = *(const bf16x8*)(xb + abase[rep] + kbeg);
    const float* pBb = pB0 + (size_t)kbeg * (2 * DFF);
    f32x4 bR0 = *(const f32x4*)pBb;
    f32x4 bR1 = *(const f32x4*)(pBb + 2 * DFF);
    f32x4 bR2 = *(const f32x4*)(pBb + (size_t)32 * 2 * DFF);
    f32x4 bR3 = *(const f32x4*)(pBb + (size_t)33 * 2 * DFF);
    for (int k0 = kbeg; k0 < kbeg + KB; k0 += 64) {
        #pragma unroll
        for (int rep = 0; rep < 8; rep++)
            *(bf16x8*)As[ac][rep * 32 + arow8] = aR[rep];
        #pragma unroll
        for (int j = 0; j < 4; j++) {
            *(unsigned*)&Bsel[kgB][nq * 4 + j][wq]     = pk2bf(bR0[j], bR1[j]);
            *(unsigned*)&Bsel[kgB + 4][nq * 4 + j][wq] = pk2bf(bR2[j], bR3[j]);
        }
        int kn = k0 + 64;
        if (kn < kbeg + KB) {
            #pragma unroll
            for (int rep = 0; rep < 8; rep++)
                aR[rep] = *(const bf16x8*)(xb + abase[rep] + kn);
            const float* pB = pB0 + (size_t)kn * (2 * DFF);
            bR0 = *(const f32x4*)pB;
            bR1 = *(const f32x4*)(pB + 2 * DFF);
            bR2 = *(const f32x4*)(pB + (size_t)32 * 2 * DFF);
            bR3 = *(const f32x4*)(pB + (size_t)33 * 2 * DFF);
        }
        __syncthreads();
        #pragma unroll
        for (int kh = 0; kh < 2; kh++) {
            bf16x8 af[4], bg[2], bu[2];
            #pragma unroll
            for (int mi = 0; mi < 4; mi++) af[mi] = *(const bf16x8*)As[kh * 4 + g][wrb + mi * 16 + lo];
            #pragma unroll
            for (int ni = 0; ni < 2; ni++) {
                bg[ni] = *(const bf16x8*)BsG[kh * 4 + g][ni * 16 + lo];
                bu[ni] = *(const bf16x8*)BsU[kh * 4 + g][ni * 16 + lo];
            }
            #pragma unroll
            for (int mi = 0; mi < 4; mi++)
                #pragma unroll
                for (int ni = 0; ni < 2; ni++) {
                    accG[mi][ni] = __builtin_amdgcn_mfma_f32_16x16x32_bf16(af[mi], bg[ni], accG[mi][ni], 0, 0, 0);
                    accU[mi][ni] = __builtin_amdgcn_mfma_f32_16x16x32_bf16(af[mi], bu[ni], accU[mi][ni], 0, 0, 0);
                }
        }
        __syncthreads();
    }
    int b = base[e];
    size_t plane = (size_t)khalf * 4096 * DFF;
    #pragma unroll
    for (int mi = 0; mi < 4; mi++)
        #pragma unroll
        for (int ni = 0; ni < 2; ni++)
            #pragma unroll
            for (int r = 0; r < 4; r++) {
                int slot = t0 + wrb + mi * 16 + g * 4 + r;
                if (slot < ce) {
                    size_t idx = plane + (size_t)(b + slot) * DFF + f0 + ni * 16 + lo;
                    pG[idx] = accG[mi][ni][r];
                    pU[idx] = accU[mi][ni][r];
                }
            }
}

// ---------------------------------------------------------------- combine: act = silu(g0+g1)*(u0+u1), bf16
// grid 2048 x 256 threads, 8 elems/thread over 4096*DFF.
__global__ __launch_bounds__(256) void moe_silu_combine(const float* __restrict__ pG,
                                                        const float* __restrict__ pU,
                                                        unsigned short* __restrict__ act) {
    size_t i = ((size_t)blockIdx.x * 256 + threadIdx.x) * 8;
    const size_t plane = (size_t)4096 * DFF;
    f32x4 g0 = *(const f32x4*)(pG + i);
    f32x4 g1 = *(const f32x4*)(pG + plane + i);
    f32x4 g2 = *(const f32x4*)(pG + i + 4);
    f32x4 g3 = *(const f32x4*)(pG + plane + i + 4);
    f32x4 u0 = *(const f32x4*)(pU + i);
    f32x4 u1 = *(const f32x4*)(pU + plane + i);
    f32x4 u2 = *(const f32x4*)(pU + i + 4);
    f32x4 u3 = *(const f32x4*)(pU + plane + i + 4);
    bf16x8 o;
    #pragma unroll
    for (int j = 0; j < 4; j++) {
        float gv = g0[j] + g1[j];
        float uv = u0[j] + u1[j];
        float a = (gv / (1.f + __expf(-gv))) * uv;
        o[j] = (short)f2bf(a);
    }
    #pragma unroll
    for (int j = 0; j < 4; j++) {
        float gv = g2[j] + g3[j];
        float uv = u2[j] + u3[j];
        float a = (gv / (1.f + __expf(-gv))) * uv;
        o[4 + j] = (short)f2bf(a);
    }
    *(bf16x8*)(act + i) = o;
}

// ---------------------------------------------------------------- MoE GEMM2: out += w * (act @ down)
// BM=256, BN=32, BK=64, depth-1 prefetch. grid (H_DIM/32, ceil(SEQ/256), NE)
__global__ __launch_bounds__(256, 4) void moe_gemm2_mfma(const unsigned short* __restrict__ act,
                                                         const float* __restrict__ down,
                                                         const int* __restrict__ toklist,
                                                         const float* __restrict__ tokw,
                                                         const int* __restrict__ cnt,
                                                         const int* __restrict__ base,
                                                         float* __restrict__ out) {
    int e = blockIdx.z;
    int ce = cnt[e];
    int t0 = blockIdx.y * 256;
    if (t0 >= ce) return;
    int c0 = blockIdx.x * 32;
    __shared__ unsigned short As[8][258][8];
    __shared__ unsigned short Bs[8][33][8];
    int t = threadIdx.x;
    int w = t >> 6, lane = t & 63, lo = lane & 15, g = lane >> 4;
    int wrb = w * 64;
    int b = base[e];
    f32x4 acc[4][2];
    #pragma unroll
    for (int mi = 0; mi < 4; mi++)
        #pragma unroll
        for (int ni = 0; ni < 2; ni++) acc[mi][ni] = (f32x4){0.f, 0.f, 0.f, 0.f};
    int arow8 = t >> 3, ac = t & 7;
    size_t abase[8];
    #pragma unroll
    for (int rep = 0; rep < 8; rep++) {
        int slot = t0 + rep * 32 + arow8;
        abase[rep] = (size_t)(b + (slot < ce ? slot : t0)) * DFF + ac * 8;
    }
    int tt = t & 127;
    int rp = tt >> 3, nq = tt & 7;
    int kgB = rp >> 2, wq = (rp & 3) * 2;
    const float* pB0 = down + (size_t)e * DFF * H_DIM + (size_t)(2 * rp) * H_DIM + c0 + nq * 4;
    bool stageB = (t < 128);
    // prologue
    bf16x8 aR[8];
    #pragma unroll
    for (int rep = 0; rep < 8; rep++) aR[rep] = *(const bf16x8*)(act + abase[rep]);
    f32x4 bR0 = (f32x4){0.f,0.f,0.f,0.f}, bR1 = bR0, bR2 = bR0, bR3 = bR0;
    if (stageB) {
        bR0 = *(const f32x4*)pB0;
        bR1 = *(const f32x4*)(pB0 + H_DIM);
        bR2 = *(const f32x4*)(pB0 + (size_t)32 * H_DIM);
        bR3 = *(const f32x4*)(pB0 + (size_t)33 * H_DIM);
    }
    for (int k0 = 0; k0 < DFF; k0 += 64) {
        #pragma unroll
        for (int rep = 0; rep < 8; rep++)
            *(bf16x8*)As[ac][rep * 32 + arow8] = aR[rep];
        if (stageB) {
            #pragma unroll
            for (int j = 0; j < 4; j++) {
                *(unsigned*)&Bs[kgB][nq * 4 + j][wq]     = pk2bf(bR0[j], bR1[j]);
                *(unsigned*)&Bs[kgB + 4][nq * 4 + j][wq] = pk2bf(bR2[j], bR3[j]);
            }
        }
        int kn = k0 + 64;
        if (kn < DFF) {
            #pragma unroll
            for (int rep = 0; rep < 8; rep++)
                aR[rep] = *(const bf16x8*)(act + abase[rep] + kn);
            if (stageB) {
                const float* pB = pB0 + (size_t)kn * H_DIM;
                bR0 = *(const f32x4*)pB;
                bR1 = *(const f32x4*)(pB + H_DIM);
                bR2 = *(const f32x4*)(pB + (size_t)32 * H_DIM);
                bR3 = *(const f32x4*)(pB + (size_t)33 * H_DIM);
            }
        }
        __syncthreads();
        #pragma unroll
        for (int kh = 0; kh < 2; kh++) {
            bf16x8 af[4], bfr[2];
            #pragma unroll
            for (int mi = 0; mi < 4; mi++) af[mi] = *(const bf16x8*)As[kh * 4 + g][wrb + mi * 16 + lo];
            #pragma unroll
            for (int ni = 0; ni < 2; ni++) bfr[ni] = *(const bf16x8*)Bs[kh * 4 + g][ni * 16 + lo];
            #pragma unroll
            for (int mi = 0; mi < 4; mi++)
                #pragma unroll
                for (int ni = 0; ni < 2; ni++)
                    acc[mi][ni] = __builtin_amdgcn_mfma_f32_16x16x32_bf16(af[mi], bfr[ni], acc[mi][ni], 0, 0, 0);
        }
        __syncthreads();
    }
    #pragma unroll
    for (int mi = 0; mi < 4; mi++)
        #pragma unroll
        for (int r = 0; r < 4; r++) {
            int slot = t0 + wrb + mi * 16 + g * 4 + r;
            if (slot < ce) {
                int tok = toklist[e * SEQ + slot];
                float wt = tokw[e * SEQ + slot];
                #pragma unroll
                for (int ni = 0; ni < 2; ni++)
                    atomicAdd(&out[(size_t)tok * H_DIM + c0 + ni * 16 + lo],
                              wt * acc[mi][ni][r]);
            }
        }
}

// ---------------------------------------------------------------- launch
extern "C" void kernel_launch(void* const* d_in, const int* in_sizes, int n_in,
                              void* d_out, int out_size, void* d_ws, size_t ws_size,
                              hipStream_t stream) {
    const float* hidden     = (const float*)d_in[0];
    const int*   positions  = (const int*)d_in[1];
    const float* in_norm_w  = (const float*)d_in[2];
    const float* post_norm_w= (const float*)d_in[3];
    const float* qkv_w      = (const float*)d_in[4];
    const float* o_w        = (const float*)d_in[5];
    const float* gate_w     = (const float*)d_in[6];
    const float* gate_bias  = (const float*)d_in[7];
    const float* gate_up_w  = (const float*)d_in[8];
    const float* down_w     = (const float*)d_in[9];
    float* out = (float*)d_out;

    float* ws   = (float*)d_ws;
    float* h2   = ws;                                  // 1024*2048 f32
    float* x    = h2  + (size_t)SEQ * H_DIM;           // 1024*2048 f32
    float* tokw = x   + (size_t)SEQ * H_DIM;           // 16*1024
    int* toklist = (int*)(tokw + NE * SEQ);            // 16*1024
    int* cnt  = toklist + NE * SEQ;                    // 16
    int* base = cnt + NE;                              // 16
    unsigned short* hb = (unsigned short*)(base + NE); // 1024*2048 bf16
    unsigned short* ob = hb + (size_t)SEQ * H_DIM;     // 1024*2048
    unsigned short* xbuf = ob + (size_t)SEQ * H_DIM;   // 1024*2048
    unsigned short* act = xbuf + (size_t)SEQ * H_DIM;  // 4096*1024
    unsigned short* Qb = act + (size_t)4 * SEQ * DFF;  // 16*1024*128
    unsigned short* Kb = Qb + (size_t)NH * SEQ * HD;   // 4*1024*128
    unsigned short* Vt = Kb + (size_t)NKV * SEQ * HD;  // 4*128*1024
    unsigned short* qkvT = Vt + (size_t)NKV * HD * SEQ;        // 3072*2048
    unsigned short* oT   = qkvT + (size_t)QKV_N * H_DIM;       // 2048*2048
    float* pG = (float*)(oT + (size_t)H_DIM * H_DIM);          // 2*4096*1024 f32
    float* pU = pG + (size_t)2 * 4096 * DFF;                   // 2*4096*1024 f32

    // 0. small weight transposes only (qkv_w, o_w)
    w2bfT<<<dim3(QKV_N / 64, H_DIM / 64, 1), 256, 0, stream>>>(qkv_w, qkvT, H_DIM, QKV_N);
    w2bfT<<<dim3(H_DIM / 64, H_DIM / 64, 1), 256, 0, stream>>>(o_w, oT, H_DIM, H_DIM);

    // 1. pre-attention RMSNorm -> bf16
    rmsnorm_dual<<<SEQ, 256, 0, stream>>>(hidden, in_norm_w, nullptr, hb);
    // 2. qkv projection fused with RoPE + bf16/transpose pack
    gemm_qkv_rope<<<dim3(QKV_N / 128, SEQ / 64), 128, 0, stream>>>(hb, qkvT, positions, Qb, Kb, Vt);
    // 3. flash attention (bf16 MFMA), mirrored q-pair x kv-half split -> ob bf16
    attn_mfma<<<dim3(SEQ / 32, NH), 256, 0, stream>>>(Qb, Kb, Vt, ob);
    // 4. o projection + residual -> h2 and d_out
    gemm_bf16<<<dim3(H_DIM / 64, SEQ / 128), 256, 0, stream>>>(ob, oT, h2, out, hidden,
                                                               SEQ, H_DIM, H_DIM);
    // 5. post-attention RMSNorm -> x (f32 for router) + xbuf (bf16 for MoE)
    rmsnorm_dual<<<SEQ, 256, 0, stream>>>(h2, post_norm_w, x, xbuf);
    // 6. router
    (void)hipMemsetAsync(cnt, 0, NE * sizeof(int), stream);
    router_kernel<<<SEQ, 256, 0, stream>>>(x, gate_w, gate_bias, toklist, tokw, cnt);
    prefix_kernel<<<1, 64, 0, stream>>>(cnt, base);
    // 7. MoE: gemm1 split-K x2 -> f32 partials -> silu combine -> gemm2
    moe_gemm1_mfma<<<dim3(DFF / 32, (SEQ / 256) * 2, NE), 256, 0, stream>>>(xbuf, gate_up_w, toklist,
                                                                            cnt, base, pG, pU);
    moe_silu_combine<<<(4096 * DFF) / (256 * 8), 256, 0, stream>>>(pG, pU, act);
    moe_gemm2_mfma<<<dim3(H_DIM / 32, SEQ / 256, NE), 256, 0, stream>>>(act, down_w, toklist, tokw, cnt, base, out);
}

// Round 21
// 381.220 us; speedup vs baseline: 1.0423x; 1.0423x over previous
//
#include <hip/hip_runtime.h>
#include <hip/hip_bf16.h>
#include <math.h>

#define H_DIM   2048
#define NH      16
#define NKV     4
#define HD      128
#define NE      16
#define TOPK    4
#define DFF     1024
#define NG      4
#define SEQ     1024
#define QKV_N   3072          // (NH + 2*NKV)*HD
#define EPS_RMS 1e-6f
#define THETA   1000000.0f

typedef __attribute__((ext_vector_type(8))) short bf16x8;
typedef __attribute__((ext_vector_type(4))) short s16x4;
typedef __attribute__((ext_vector_type(4))) float f32x4;

__device__ inline unsigned short f2bf(float x) {
    unsigned u = __builtin_bit_cast(unsigned, x);
    unsigned r = (u + 0x7FFFu + ((u >> 16) & 1u)) >> 16;
    return (unsigned short)r;
}

// pack two floats -> u32 of 2 bf16 (lo, hi); lowers to v_cvt_pk_bf16_f32
__device__ inline unsigned pk2bf(float lo, float hi) {
    __hip_bfloat162 h = __float22bfloat162_rn(float2{lo, hi});
    unsigned r;
    __builtin_memcpy(&r, &h, 4);
    return r;
}

// ---------------------------------------------------------------- weight transpose + bf16 convert (small weights only)
__global__ __launch_bounds__(256) void w2bfT(const float* __restrict__ in,
                                             unsigned short* __restrict__ out,
                                             int K, int N) {
    const float* src = in + (size_t)blockIdx.z * K * N;
    unsigned short* dst = out + (size_t)blockIdx.z * K * N;
    int n0 = blockIdx.x * 64, k0 = blockIdx.y * 64;
    __shared__ unsigned short tile[64][66];
    int tid = threadIdx.x, c = tid & 63, r4 = tid >> 6;
    #pragma unroll
    for (int rep = 0; rep < 16; rep++) {
        int r = rep * 4 + r4;
        tile[r][c] = f2bf(src[(size_t)(k0 + r) * N + n0 + c]);
    }
    __syncthreads();
    #pragma unroll
    for (int rep = 0; rep < 16; rep++) {
        int r = rep * 4 + r4;
        dst[(size_t)(n0 + r) * K + k0 + c] = tile[c][r];
    }
}

// ---------------------------------------------------------------- RMSNorm (f32 in, optional f32 + bf16 out)
__global__ __launch_bounds__(256) void rmsnorm_dual(const float* __restrict__ in,
                                                    const float* __restrict__ w,
                                                    float* __restrict__ outf,
                                                    unsigned short* __restrict__ outb) {
    int t = blockIdx.x;
    const float* xt = in + (size_t)t * H_DIM;
    float ss = 0.f;
    for (int d = threadIdx.x * 4; d < H_DIM; d += 1024) {
        float4 v = *reinterpret_cast<const float4*>(xt + d);
        ss += v.x * v.x + v.y * v.y + v.z * v.z + v.w * v.w;
    }
    for (int off = 1; off < 64; off <<= 1) ss += __shfl_xor(ss, off);
    __shared__ float red[4];
    __shared__ float srms;
    if ((threadIdx.x & 63) == 0) red[threadIdx.x >> 6] = ss;
    __syncthreads();
    if (threadIdx.x == 0)
        srms = rsqrtf((red[0] + red[1] + red[2] + red[3]) * (1.f / H_DIM) + EPS_RMS);
    __syncthreads();
    float r = srms;
    for (int d = threadIdx.x * 4; d < H_DIM; d += 1024) {
        float4 v  = *reinterpret_cast<const float4*>(xt + d);
        float4 wv = *reinterpret_cast<const float4*>(w + d);
        float4 ov;
        ov.x = v.x * r * wv.x; ov.y = v.y * r * wv.y;
        ov.z = v.z * r * wv.z; ov.w = v.w * r * wv.w;
        if (outf) *reinterpret_cast<float4*>(outf + (size_t)t * H_DIM + d) = ov;
        if (outb) {
            s16x4 bv = (s16x4){(short)f2bf(ov.x), (short)f2bf(ov.y),
                               (short)f2bf(ov.z), (short)f2bf(ov.w)};
            *reinterpret_cast<s16x4*>(outb + (size_t)t * H_DIM + d) = bv;
        }
    }
}

// ---------------------------------------------------------------- qkv GEMM (Bt bf16) fused RoPE + pack
// BM=64 (2 waves x 32 rows), BN=128 (=1 head), BK=64. 128 threads. grid (24, SEQ/64)
__global__ __launch_bounds__(128) void gemm_qkv_rope(const unsigned short* __restrict__ A,
                                                     const unsigned short* __restrict__ Bt,
                                                     const int* __restrict__ positions,
                                                     unsigned short* __restrict__ Qb,
                                                     unsigned short* __restrict__ Kb,
                                                     unsigned short* __restrict__ Vt) {
    __shared__ unsigned short As[8][66][8];    // [kg][row][k&7], +2 row pad
    __shared__ unsigned short Bs[8][130][8];
    int xb = blockIdx.x;                       // 0..23: 0-15 Q heads, 16-19 K, 20-23 V
    int row0 = blockIdx.y * 64, col0 = xb * 128;
    int t = threadIdx.x;
    int w = t >> 6, lane = t & 63, lo = lane & 15, g = lane >> 4;
    int wr = w * 32;
    f32x4 acc[2][8];
    #pragma unroll
    for (int mi = 0; mi < 2; mi++)
        #pragma unroll
        for (int ni = 0; ni < 8; ni++) acc[mi][ni] = (f32x4){0.f, 0.f, 0.f, 0.f};
    int arow8 = t >> 3, ac = t & 7;            // 16 rows per pass, 8 lanes/row
    size_t aoff[4], boff[8];
    #pragma unroll
    for (int rep = 0; rep < 4; rep++)
        aoff[rep] = (size_t)(row0 + rep * 16 + arow8) * H_DIM + ac * 8;
    #pragma unroll
    for (int rep = 0; rep < 8; rep++)
        boff[rep] = (size_t)(col0 + rep * 16 + arow8) * H_DIM + ac * 8;
    bf16x8 aR[4], bR[8];
    #pragma unroll
    for (int rep = 0; rep < 4; rep++) aR[rep] = *(const bf16x8*)(A + aoff[rep]);
    #pragma unroll
    for (int rep = 0; rep < 8; rep++) bR[rep] = *(const bf16x8*)(Bt + boff[rep]);
    for (int k0 = 0; k0 < H_DIM; k0 += 64) {
        #pragma unroll
        for (int rep = 0; rep < 4; rep++)
            *(bf16x8*)As[ac][rep * 16 + arow8] = aR[rep];
        #pragma unroll
        for (int rep = 0; rep < 8; rep++)
            *(bf16x8*)Bs[ac][rep * 16 + arow8] = bR[rep];
        int kn = k0 + 64;
        if (kn < H_DIM) {
            #pragma unroll
            for (int rep = 0; rep < 4; rep++) aR[rep] = *(const bf16x8*)(A + aoff[rep] + kn);
            #pragma unroll
            for (int rep = 0; rep < 8; rep++) bR[rep] = *(const bf16x8*)(Bt + boff[rep] + kn);
        }
        __syncthreads();
        #pragma unroll
        for (int kh = 0; kh < 2; kh++) {
            bf16x8 af[2], bfr[8];
            #pragma unroll
            for (int mi = 0; mi < 2; mi++) af[mi] = *(const bf16x8*)As[kh * 4 + g][wr + mi * 16 + lo];
            #pragma unroll
            for (int ni = 0; ni < 8; ni++) bfr[ni] = *(const bf16x8*)Bs[kh * 4 + g][ni * 16 + lo];
            #pragma unroll
            for (int mi = 0; mi < 2; mi++)
                #pragma unroll
                for (int ni = 0; ni < 8; ni++)
                    acc[mi][ni] = __builtin_amdgcn_mfma_f32_16x16x32_bf16(af[mi], bfr[ni], acc[mi][ni], 0, 0, 0);
        }
        __syncthreads();
    }
    if (xb < NH + NKV) {
        bool isQ = (xb < NH);
        unsigned short* dst = isQ ? (Qb + (size_t)xb * SEQ * HD)
                                  : (Kb + (size_t)(xb - NH) * SEQ * HD);
        float qs = isQ ? 0.08838834764831845f : 1.0f;
        float invf[4];
        #pragma unroll
        for (int ni = 0; ni < 4; ni++)
            invf[ni] = __powf(THETA, -(float)(ni * 16 + lo) * (1.0f / 64.0f));
        #pragma unroll
        for (int mi = 0; mi < 2; mi++)
            #pragma unroll
            for (int r = 0; r < 4; r++) {
                int tok = row0 + wr + mi * 16 + g * 4 + r;
                float pos = (float)positions[tok];
                #pragma unroll
                for (int ni = 0; ni < 4; ni++) {
                    float s, c;
                    __sincosf(pos * invf[ni], &s, &c);
                    float x1 = acc[mi][ni][r], x2 = acc[mi][ni + 4][r];
                    int d = ni * 16 + lo;
                    dst[(size_t)tok * HD + d]      = f2bf((x1 * c - x2 * s) * qs);
                    dst[(size_t)tok * HD + d + 64] = f2bf((x2 * c + x1 * s) * qs);
                }
            }
    } else {
        int kvh = xb - (NH + NKV);
        #pragma unroll
        for (int mi = 0; mi < 2; mi++)
            #pragma unroll
            for (int ni = 0; ni < 8; ni++) {
                int tok0 = row0 + wr + mi * 16 + g * 4;
                int d = ni * 16 + lo;
                ushort4 v4;
                v4.x = f2bf(acc[mi][ni][0]);
                v4.y = f2bf(acc[mi][ni][1]);
                v4.z = f2bf(acc[mi][ni][2]);
                v4.w = f2bf(acc[mi][ni][3]);
                *reinterpret_cast<ushort4*>(Vt + ((size_t)kvh * HD + d) * SEQ + tok0) = v4;
            }
    }
}

// ---------------------------------------------------------------- o-proj GEMM (Bt bf16) + residual
// BM=128, BN=64, BK=64. 256 threads. grid (N/64, M/128).
__global__ __launch_bounds__(256) void gemm_bf16(const unsigned short* __restrict__ A,
                                                 const unsigned short* __restrict__ Bt,
                                                 float* __restrict__ C,
                                                 float* __restrict__ C2,
                                                 const float* __restrict__ R,
                                                 int M, int N, int K) {
    __shared__ unsigned short As[8][130][8];
    __shared__ unsigned short Bs[8][66][8];
    int row0 = blockIdx.y * 128, col0 = blockIdx.x * 64;
    int t = threadIdx.x;
    int w = t >> 6, lane = t & 63, lo = lane & 15, g = lane >> 4;
    int wr = (w >> 1) * 64, wc = (w & 1) * 32;
    f32x4 acc[4][2];
    #pragma unroll
    for (int mi = 0; mi < 4; mi++)
        #pragma unroll
        for (int ni = 0; ni < 2; ni++) acc[mi][ni] = (f32x4){0.f, 0.f, 0.f, 0.f};
    int arow8 = t >> 3, ac = t & 7;
    size_t aoff[4], boff[2];
    #pragma unroll
    for (int rep = 0; rep < 4; rep++)
        aoff[rep] = (size_t)(row0 + rep * 32 + arow8) * K + ac * 8;
    #pragma unroll
    for (int rep = 0; rep < 2; rep++)
        boff[rep] = (size_t)(col0 + rep * 32 + arow8) * K + ac * 8;
    bf16x8 aR[4], bR[2];
    #pragma unroll
    for (int rep = 0; rep < 4; rep++) aR[rep] = *(const bf16x8*)(A + aoff[rep]);
    #pragma unroll
    for (int rep = 0; rep < 2; rep++) bR[rep] = *(const bf16x8*)(Bt + boff[rep]);
    for (int k0 = 0; k0 < K; k0 += 64) {
        #pragma unroll
        for (int rep = 0; rep < 4; rep++)
            *(bf16x8*)As[ac][rep * 32 + arow8] = aR[rep];
        #pragma unroll
        for (int rep = 0; rep < 2; rep++)
            *(bf16x8*)Bs[ac][rep * 32 + arow8] = bR[rep];
        int kn = k0 + 64;
        if (kn < K) {
            #pragma unroll
            for (int rep = 0; rep < 4; rep++) aR[rep] = *(const bf16x8*)(A + aoff[rep] + kn);
            #pragma unroll
            for (int rep = 0; rep < 2; rep++) bR[rep] = *(const bf16x8*)(Bt + boff[rep] + kn);
        }
        __syncthreads();
        #pragma unroll
        for (int kh = 0; kh < 2; kh++) {
            bf16x8 af[4], bfr[2];
            #pragma unroll
            for (int mi = 0; mi < 4; mi++) af[mi] = *(const bf16x8*)As[kh * 4 + g][wr + mi * 16 + lo];
            #pragma unroll
            for (int ni = 0; ni < 2; ni++) bfr[ni] = *(const bf16x8*)Bs[kh * 4 + g][wc + ni * 16 + lo];
            #pragma unroll
            for (int mi = 0; mi < 4; mi++)
                #pragma unroll
                for (int ni = 0; ni < 2; ni++)
                    acc[mi][ni] = __builtin_amdgcn_mfma_f32_16x16x32_bf16(af[mi], bfr[ni], acc[mi][ni], 0, 0, 0);
        }
        __syncthreads();
    }
    #pragma unroll
    for (int mi = 0; mi < 4; mi++)
        #pragma unroll
        for (int ni = 0; ni < 2; ni++)
            #pragma unroll
            for (int r = 0; r < 4; r++) {
                int row = row0 + wr + mi * 16 + g * 4 + r;
                int col = col0 + wc + ni * 16 + lo;
                size_t idx = (size_t)row * N + col;
                float v = acc[mi][ni][r];
                if (R)  v += R[idx];
                C[idx] = v;
                if (C2) C2[idx] = v;
            }
}

// ---------------------------------------------------------------- flash attention, 4 waves / block:
// (mirrored q-pair) x (kv-half split) -> 8 waves/CU, halved critical path.
__global__ __launch_bounds__(256) void attn_mfma(const unsigned short* __restrict__ Qb,
                                                 const unsigned short* __restrict__ Kb,
                                                 const unsigned short* __restrict__ Vt,
                                                 unsigned short* __restrict__ ob) {
    int bx = blockIdx.x;
    int h  = blockIdx.y;
    int kvh = h >> 2;
    int tid = threadIdx.x;
    int wid = tid >> 6;
    int qsel = wid >> 1, khalf = wid & 1;
    int qt = qsel ? (SEQ / 16 - 1 - bx) : bx;
    int q0 = qt * 16;
    int l = tid & 63;
    int lo = l & 15, g = l >> 4;

    __shared__ alignas(16) unsigned short pbuf[4][16][40];
    __shared__ float obuf[2][16][128];
    __shared__ float mbuf[2][16], lbuf[2][16];

    bf16x8 qf[4];
    const unsigned short* qp = Qb + ((size_t)h * SEQ + q0 + lo) * HD + g * 8;
    #pragma unroll
    for (int ks = 0; ks < 4; ks++)
        qf[ks] = *(const bf16x8*)(qp + ks * 32);

    f32x4 accO[8];
    #pragma unroll
    for (int nd = 0; nd < 8; nd++) accO[nd] = (f32x4){0.f, 0.f, 0.f, 0.f};
    float mrun[4], lrun[4];
    #pragma unroll
    for (int r = 0; r < 4; r++) { mrun[r] = -INFINITY; lrun[r] = 0.f; }

    int nc = (q0 + 16 + 31) / 32;
    int ncH = (nc + 1) >> 1;
    int cbeg = khalf ? ncH : 0;
    int cend = khalf ? nc : ncH;
    for (int ch = cbeg; ch < cend; ch++) {
        int kv0 = ch * 32;
        f32x4 accS[2];
        accS[0] = (f32x4){0.f, 0.f, 0.f, 0.f};
        accS[1] = (f32x4){0.f, 0.f, 0.f, 0.f};
        const unsigned short* kp = Kb + ((size_t)kvh * SEQ + kv0 + lo) * HD + g * 8;
        #pragma unroll
        for (int n = 0; n < 2; n++) {
            const unsigned short* kpn = kp + (size_t)n * 16 * HD;
            #pragma unroll
            for (int ks = 0; ks < 4; ks++) {
                bf16x8 kf = *(const bf16x8*)(kpn + ks * 32);
                accS[n] = __builtin_amdgcn_mfma_f32_16x16x32_bf16(qf[ks], kf, accS[n], 0, 0, 0);
            }
        }
        if (ch == nc - 1) {
            #pragma unroll
            for (int n = 0; n < 2; n++)
                #pragma unroll
                for (int r = 0; r < 4; r++) {
                    int kv = kv0 + n * 16 + lo;
                    int q  = q0 + g * 4 + r;
                    if (kv > q) accS[n][r] = -1e30f;
                }
        }
        float mt[4], fac[4];
        #pragma unroll
        for (int r = 0; r < 4; r++) {
            float m = fmaxf(accS[0][r], accS[1][r]);
            #pragma unroll
            for (int off = 1; off < 16; off <<= 1) m = fmaxf(m, __shfl_xor(m, off));
            mt[r] = fmaxf(mrun[r], m);
            fac[r] = __expf(mrun[r] - mt[r]);
        }
        float psum[4] = {0.f, 0.f, 0.f, 0.f};
        #pragma unroll
        for (int n = 0; n < 2; n++)
            #pragma unroll
            for (int r = 0; r < 4; r++) {
                float p = __expf(accS[n][r] - mt[r]);
                psum[r] += p;
                pbuf[wid][g * 4 + r][n * 16 + lo] = f2bf(p);
            }
        #pragma unroll
        for (int r = 0; r < 4; r++) {
            float s = psum[r];
            #pragma unroll
            for (int off = 1; off < 16; off <<= 1) s += __shfl_xor(s, off);
            lrun[r] = lrun[r] * fac[r] + s;
            mrun[r] = mt[r];
        }
        #pragma unroll
        for (int nd = 0; nd < 8; nd++)
            #pragma unroll
            for (int r = 0; r < 4; r++) accO[nd][r] *= fac[r];
        __builtin_amdgcn_sched_barrier(0);
        bf16x8 pf = *(const bf16x8*)(&pbuf[wid][lo][g * 8]);
        const unsigned short* vp = Vt + ((size_t)kvh * HD + lo) * SEQ + kv0 + g * 8;
        #pragma unroll
        for (int nd = 0; nd < 8; nd++) {
            bf16x8 vf = *(const bf16x8*)(vp + (size_t)nd * 16 * SEQ);
            accO[nd] = __builtin_amdgcn_mfma_f32_16x16x32_bf16(pf, vf, accO[nd], 0, 0, 0);
        }
        __builtin_amdgcn_sched_barrier(0);
    }
    // kv-half merge: wave khalf=1 publishes partials; khalf=0 merges + writes out
    if (khalf) {
        #pragma unroll
        for (int r = 0; r < 4; r++) {
            if (lo == 0) {
                mbuf[qsel][g * 4 + r] = mrun[r];
                lbuf[qsel][g * 4 + r] = lrun[r];
            }
            #pragma unroll
            for (int nd = 0; nd < 8; nd++)
                obuf[qsel][g * 4 + r][nd * 16 + lo] = accO[nd][r];
        }
    }
    __syncthreads();
    if (!khalf) {
        #pragma unroll
        for (int r = 0; r < 4; r++) {
            int row = g * 4 + r;
            float m1 = mbuf[qsel][row], l1 = lbuf[qsel][row];
            float m0 = mrun[r], l0 = lrun[r];
            float m = fmaxf(m0, m1);
            float f0 = (l0 > 0.f) ? __expf(m0 - m) : 0.f;
            float f1 = (l1 > 0.f) ? __expf(m1 - m) : 0.f;
            float linv = 1.f / (l0 * f0 + l1 * f1);
            #pragma unroll
            for (int nd = 0; nd < 8; nd++) {
                float v = (accO[nd][r] * f0 + obuf[qsel][row][nd * 16 + lo] * f1) * linv;
                ob[(size_t)(q0 + row) * H_DIM + h * HD + nd * 16 + lo] = f2bf(v);
            }
        }
    }
}

// ---------------------------------------------------------------- router (wave-parallel: 4 waves x 4 experts)
__global__ __launch_bounds__(256) void router_kernel(const float* __restrict__ x,
                                                     const float* __restrict__ gate_w,
                                                     const float* __restrict__ gate_bias,
                                                     int* __restrict__ toklist,
                                                     float* __restrict__ tokw,
                                                     int* __restrict__ cnt) {
    int t = blockIdx.x;
    const float* xt = x + (size_t)t * H_DIM;
    __shared__ float logits[NE];
    int wid = threadIdx.x >> 6, lane = threadIdx.x & 63;
    #pragma unroll
    for (int i = 0; i < 4; i++) {
        int e = wid * 4 + i;
        const float* gw = gate_w + (size_t)e * H_DIM;
        float p = 0.f;
        for (int d = lane * 4; d < H_DIM; d += 256) {
            float4 xv = *reinterpret_cast<const float4*>(xt + d);
            float4 wv = *reinterpret_cast<const float4*>(gw + d);
            p += xv.x * wv.x + xv.y * wv.y + xv.z * wv.z + xv.w * wv.w;
        }
        #pragma unroll
        for (int off = 1; off < 64; off <<= 1) p += __shfl_xor(p, off);
        if (lane == 0) logits[e] = p;
    }
    __syncthreads();
    if (threadIdx.x == 0) {
        float sig[NE], sb[NE];
        for (int e = 0; e < NE; e++) {
            sig[e] = 1.f / (1.f + expf(-logits[e]));
            sb[e] = sig[e] + gate_bias[e];
        }
        float gs[NG];
        for (int g = 0; g < NG; g++) {
            float m1 = -1e30f, m2 = -1e30f;
            for (int i = 0; i < 4; i++) {
                float v = sb[g * 4 + i];
                if (v > m1) { m2 = m1; m1 = v; } else if (v > m2) m2 = v;
            }
            gs[g] = m1 + m2;
        }
        int g1 = 0;
        for (int g = 1; g < NG; g++) if (gs[g] > gs[g1]) g1 = g;
        int g2 = -1;
        for (int g = 0; g < NG; g++) {
            if (g == g1) continue;
            if (g2 < 0 || gs[g] > gs[g2]) g2 = g;
        }
        bool allowed[NE], used[NE];
        for (int e = 0; e < NE; e++) { int g = e >> 2; allowed[e] = (g == g1 || g == g2); used[e] = false; }
        int sel[TOPK]; float wsel[TOPK]; float wsum = 0.f;
        for (int k = 0; k < TOPK; k++) {
            int best = -1; float bv = -1e30f;
            for (int e = 0; e < NE; e++) {
                if (!allowed[e] || used[e]) continue;
                if (best < 0 || sb[e] > bv) { best = e; bv = sb[e]; }
            }
            used[best] = true; sel[k] = best; wsel[k] = sig[best]; wsum += sig[best];
        }
        float invs = 1.f / (wsum + 1e-20f);
        for (int k = 0; k < TOPK; k++) {
            int e = sel[k];
            int slot = atomicAdd(&cnt[e], 1);
            toklist[e * SEQ + slot] = t;
            tokw[e * SEQ + slot] = wsel[k] * invs;
        }
    }
}

__global__ void prefix_kernel(const int* __restrict__ cnt, int* __restrict__ base) {
    if (threadIdx.x == 0) {
        int s = 0;
        for (int e = 0; e < NE; e++) { base[e] = s; s += cnt[e]; }
    }
}

// ---------------------------------------------------------------- MoE GEMM1: act = silu(x@G)*(x@U)
// BM=256, BN=32 (G and U each), BK=64, depth-1 prefetch (R14 proven).
// grid (DFF/32, ceil(SEQ/256), NE)
__global__ __launch_bounds__(256, 2) void moe_gemm1_mfma(const unsigned short* __restrict__ xb,
                                                         const float* __restrict__ gup,
                                                         const int* __restrict__ toklist,
                                                         const int* __restrict__ cnt,
                                                         const int* __restrict__ base,
                                                         unsigned short* __restrict__ act) {
    int e = blockIdx.z;
    int ce = cnt[e];
    int t0 = blockIdx.y * 256;
    if (t0 >= ce) return;
    int f0 = blockIdx.x * 32;
    __shared__ unsigned short As[8][258][8];   // [kg][row][k&7]
    __shared__ unsigned short BsG[8][33][8];
    __shared__ unsigned short BsU[8][33][8];
    __shared__ int toks[256];
    int t = threadIdx.x;
    { int s = t0 + t; toks[t] = toklist[e * SEQ + (s < ce ? s : 0)]; }
    __syncthreads();
    int w = t >> 6, lane = t & 63, lo = lane & 15, g = lane >> 4;
    int wrb = w * 64;
    f32x4 accG[4][2], accU[4][2];
    #pragma unroll
    for (int mi = 0; mi < 4; mi++)
        #pragma unroll
        for (int ni = 0; ni < 2; ni++) {
            accG[mi][ni] = (f32x4){0.f, 0.f, 0.f, 0.f};
            accU[mi][ni] = (f32x4){0.f, 0.f, 0.f, 0.f};
        }
    // A staging: 8 lanes per row (128B line), 32 rows per pass, 8 passes
    int arow8 = t >> 3, ac = t & 7;
    size_t abase[8];
    #pragma unroll
    for (int rep = 0; rep < 8; rep++)
        abase[rep] = (size_t)toks[rep * 32 + arow8] * H_DIM + ac * 8;
    // B staging: t<128 -> G, t>=128 -> U; rows {2rp,2rp+1,2rp+32,2rp+33}, cols nq*4..+3
    int half = t >> 7, tt = t & 127;
    int rp = tt >> 3, nq = tt & 7;
    int kgB = rp >> 2, wq = (rp & 3) * 2;
    unsigned short (*Bsel)[33][8] = half ? BsU : BsG;
    const float* W = gup + (size_t)e * H_DIM * (2 * DFF);
    const float* pB0 = W + (size_t)(2 * rp) * (2 * DFF) + half * DFF + f0 + nq * 4;
    // prologue
    bf16x8 aR[8];
    #pragma unroll
    for (int rep = 0; rep < 8; rep++) aR[rep] = *(const bf16x8*)(xb + abase[rep]);
    f32x4 bR0 = *(const f32x4*)pB0;
    f32x4 bR1 = *(const f32x4*)(pB0 + 2 * DFF);
    f32x4 bR2 = *(const f32x4*)(pB0 + (size_t)32 * 2 * DFF);
    f32x4 bR3 = *(const f32x4*)(pB0 + (size_t)33 * 2 * DFF);
    for (int k0 = 0; k0 < H_DIM; k0 += 64) {
        #pragma unroll
        for (int rep = 0; rep < 8; rep++)
            *(bf16x8*)As[ac][rep * 32 + arow8] = aR[rep];
        #pragma unroll
        for (int j = 0; j < 4; j++) {
            *(unsigned*)&Bsel[kgB][nq * 4 + j][wq]     = pk2bf(bR0[j], bR1[j]);
            *(unsigned*)&Bsel[kgB + 4][nq * 4 + j][wq] = pk2bf(bR2[j], bR3[j]);
        }
        int kn = k0 + 64;
        if (kn < H_DIM) {
            #pragma unroll
            for (int rep = 0; rep < 8; rep++)
                aR[rep] = *(const bf16x8*)(xb + abase[rep] + kn);
            const float* pB = pB0 + (size_t)kn * (2 * DFF);
            bR0 = *(const f32x4*)pB;
            bR1 = *(const f32x4*)(pB + 2 * DFF);
            bR2 = *(const f32x4*)(pB + (size_t)32 * 2 * DFF);
            bR3 = *(const f32x4*)(pB + (size_t)33 * 2 * DFF);
        }
        __syncthreads();
        #pragma unroll
        for (int kh = 0; kh < 2; kh++) {
            bf16x8 af[4], bg[2], bu[2];
            #pragma unroll
            for (int mi = 0; mi < 4; mi++) af[mi] = *(const bf16x8*)As[kh * 4 + g][wrb + mi * 16 + lo];
            #pragma unroll
            for (int ni = 0; ni < 2; ni++) {
                bg[ni] = *(const bf16x8*)BsG[kh * 4 + g][ni * 16 + lo];
                bu[ni] = *(const bf16x8*)BsU[kh * 4 + g][ni * 16 + lo];
            }
            #pragma unroll
            for (int mi = 0; mi < 4; mi++)
                #pragma unroll
                for (int ni = 0; ni < 2; ni++) {
                    accG[mi][ni] = __builtin_amdgcn_mfma_f32_16x16x32_bf16(af[mi], bg[ni], accG[mi][ni], 0, 0, 0);
                    accU[mi][ni] = __builtin_amdgcn_mfma_f32_16x16x32_bf16(af[mi], bu[ni], accU[mi][ni], 0, 0, 0);
                }
        }
        __syncthreads();
    }
    int b = base[e];
    #pragma unroll
    for (int mi = 0; mi < 4; mi++)
        #pragma unroll
        for (int ni = 0; ni < 2; ni++)
            #pragma unroll
            for (int r = 0; r < 4; r++) {
                int slot = t0 + wrb + mi * 16 + g * 4 + r;
                if (slot < ce) {
                    float gv = accG[mi][ni][r], uv = accU[mi][ni][r];
                    float a = (gv / (1.f + __expf(-gv))) * uv;
                    act[(size_t)(b + slot) * DFF + f0 + ni * 16 + lo] = f2bf(a);
                }
            }
}

// ---------------------------------------------------------------- MoE GEMM2: out += w * (act @ down)
// BM=256, BN=32, BK=64, depth-1 prefetch. grid (H_DIM/32, ceil(SEQ/256), NE)
__global__ __launch_bounds__(256, 4) void moe_gemm2_mfma(const unsigned short* __restrict__ act,
                                                         const float* __restrict__ down,
                                                         const int* __restrict__ toklist,
                                                         const float* __restrict__ tokw,
                                                         const int* __restrict__ cnt,
                                                         const int* __restrict__ base,
                                                         float* __restrict__ out) {
    int e = blockIdx.z;
    int ce = cnt[e];
    int t0 = blockIdx.y * 256;
    if (t0 >= ce) return;
    int c0 = blockIdx.x * 32;
    __shared__ unsigned short As[8][258][8];
    __shared__ unsigned short Bs[8][33][8];
    int t = threadIdx.x;
    int w = t >> 6, lane = t & 63, lo = lane & 15, g = lane >> 4;
    int wrb = w * 64;
    int b = base[e];
    f32x4 acc[4][2];
    #pragma unroll
    for (int mi = 0; mi < 4; mi++)
        #pragma unroll
        for (int ni = 0; ni < 2; ni++) acc[mi][ni] = (f32x4){0.f, 0.f, 0.f, 0.f};
    int arow8 = t >> 3, ac = t & 7;
    size_t abase[8];
    #pragma unroll
    for (int rep = 0; rep < 8; rep++) {
        int slot = t0 + rep * 32 + arow8;
        abase[rep] = (size_t)(b + (slot < ce ? slot : t0)) * DFF + ac * 8;
    }
    int tt = t & 127;
    int rp = tt >> 3, nq = tt & 7;
    int kgB = rp >> 2, wq = (rp & 3) * 2;
    const float* pB0 = down + (size_t)e * DFF * H_DIM + (size_t)(2 * rp) * H_DIM + c0 + nq * 4;
    bool stageB = (t < 128);
    // prologue
    bf16x8 aR[8];
    #pragma unroll
    for (int rep = 0; rep < 8; rep++) aR[rep] = *(const bf16x8*)(act + abase[rep]);
    f32x4 bR0 = (f32x4){0.f,0.f,0.f,0.f}, bR1 = bR0, bR2 = bR0, bR3 = bR0;
    if (stageB) {
        bR0 = *(const f32x4*)pB0;
        bR1 = *(const f32x4*)(pB0 + H_DIM);
        bR2 = *(const f32x4*)(pB0 + (size_t)32 * H_DIM);
        bR3 = *(const f32x4*)(pB0 + (size_t)33 * H_DIM);
    }
    for (int k0 = 0; k0 < DFF; k0 += 64) {
        #pragma unroll
        for (int rep = 0; rep < 8; rep++)
            *(bf16x8*)As[ac][rep * 32 + arow8] = aR[rep];
        if (stageB) {
            #pragma unroll
            for (int j = 0; j < 4; j++) {
                *(unsigned*)&Bs[kgB][nq * 4 + j][wq]     = pk2bf(bR0[j], bR1[j]);
                *(unsigned*)&Bs[kgB + 4][nq * 4 + j][wq] = pk2bf(bR2[j], bR3[j]);
            }
        }
        int kn = k0 + 64;
        if (kn < DFF) {
            #pragma unroll
            for (int rep = 0; rep < 8; rep++)
                aR[rep] = *(const bf16x8*)(act + abase[rep] + kn);
            if (stageB) {
                const float* pB = pB0 + (size_t)kn * H_DIM;
                bR0 = *(const f32x4*)pB;
                bR1 = *(const f32x4*)(pB + H_DIM);
                bR2 = *(const f32x4*)(pB + (size_t)32 * H_DIM);
                bR3 = *(const f32x4*)(pB + (size_t)33 * H_DIM);
            }
        }
        __syncthreads();
        #pragma unroll
        for (int kh = 0; kh < 2; kh++) {
            bf16x8 af[4], bfr[2];
            #pragma unroll
            for (int mi = 0; mi < 4; mi++) af[mi] = *(const bf16x8*)As[kh * 4 + g][wrb + mi * 16 + lo];
            #pragma unroll
            for (int ni = 0; ni < 2; ni++) bfr[ni] = *(const bf16x8*)Bs[kh * 4 + g][ni * 16 + lo];
            #pragma unroll
            for (int mi = 0; mi < 4; mi++)
                #pragma unroll
                for (int ni = 0; ni < 2; ni++)
                    acc[mi][ni] = __builtin_amdgcn_mfma_f32_16x16x32_bf16(af[mi], bfr[ni], acc[mi][ni], 0, 0, 0);
        }
        __syncthreads();
    }
    #pragma unroll
    for (int mi = 0; mi < 4; mi++)
        #pragma unroll
        for (int r = 0; r < 4; r++) {
            int slot = t0 + wrb + mi * 16 + g * 4 + r;
            if (slot < ce) {
                int tok = toklist[e * SEQ + slot];
                float wt = tokw[e * SEQ + slot];
                #pragma unroll
                for (int ni = 0; ni < 2; ni++)
                    atomicAdd(&out[(size_t)tok * H_DIM + c0 + ni * 16 + lo],
                              wt * acc[mi][ni][r]);
            }
        }
}

// ---------------------------------------------------------------- launch
extern "C" void kernel_launch(void* const* d_in, const int* in_sizes, int n_in,
                              void* d_out, int out_size, void* d_ws, size_t ws_size,
                              hipStream_t stream) {
    const float* hidden     = (const float*)d_in[0];
    const int*   positions  = (const int*)d_in[1];
    const float* in_norm_w  = (const float*)d_in[2];
    const float* post_norm_w= (const float*)d_in[3];
    const float* qkv_w      = (const float*)d_in[4];
    const float* o_w        = (const float*)d_in[5];
    const float* gate_w     = (const float*)d_in[6];
    const float* gate_bias  = (const float*)d_in[7];
    const float* gate_up_w  = (const float*)d_in[8];
    const float* down_w     = (const float*)d_in[9];
    float* out = (float*)d_out;

    float* ws   = (float*)d_ws;
    float* h2   = ws;                                  // 1024*2048 f32
    float* x    = h2  + (size_t)SEQ * H_DIM;           // 1024*2048 f32
    float* tokw = x   + (size_t)SEQ * H_DIM;           // 16*1024
    int* toklist = (int*)(tokw + NE * SEQ);            // 16*1024
    int* cnt  = toklist + NE * SEQ;                    // 16
    int* base = cnt + NE;                              // 16
    unsigned short* hb = (unsigned short*)(base + NE); // 1024*2048 bf16
    unsigned short* ob = hb + (size_t)SEQ * H_DIM;     // 1024*2048
    unsigned short* xbuf = ob + (size_t)SEQ * H_DIM;   // 1024*2048
    unsigned short* act = xbuf + (size_t)SEQ * H_DIM;  // 4096*1024
    unsigned short* Qb = act + (size_t)4 * SEQ * DFF;  // 16*1024*128
    unsigned short* Kb = Qb + (size_t)NH * SEQ * HD;   // 4*1024*128
    unsigned short* Vt = Kb + (size_t)NKV * SEQ * HD;  // 4*128*1024
    unsigned short* qkvT = Vt + (size_t)NKV * HD * SEQ;        // 3072*2048
    unsigned short* oT   = qkvT + (size_t)QKV_N * H_DIM;       // 2048*2048

    // 0. small weight transposes only (qkv_w, o_w)
    w2bfT<<<dim3(QKV_N / 64, H_DIM / 64, 1), 256, 0, stream>>>(qkv_w, qkvT, H_DIM, QKV_N);
    w2bfT<<<dim3(H_DIM / 64, H_DIM / 64, 1), 256, 0, stream>>>(o_w, oT, H_DIM, H_DIM);

    // 1. pre-attention RMSNorm -> bf16
    rmsnorm_dual<<<SEQ, 256, 0, stream>>>(hidden, in_norm_w, nullptr, hb);
    // 2. qkv projection fused with RoPE + bf16/transpose pack
    gemm_qkv_rope<<<dim3(QKV_N / 128, SEQ / 64), 128, 0, stream>>>(hb, qkvT, positions, Qb, Kb, Vt);
    // 3. flash attention (bf16 MFMA), mirrored q-pair x kv-half split -> ob bf16
    attn_mfma<<<dim3(SEQ / 32, NH), 256, 0, stream>>>(Qb, Kb, Vt, ob);
    // 4. o projection + residual -> h2 and d_out
    gemm_bf16<<<dim3(H_DIM / 64, SEQ / 128), 256, 0, stream>>>(ob, oT, h2, out, hidden,
                                                               SEQ, H_DIM, H_DIM);
    // 5. post-attention RMSNorm -> x (f32 for router) + xbuf (bf16 for MoE)
    rmsnorm_dual<<<SEQ, 256, 0, stream>>>(h2, post_norm_w, x, xbuf);
    // 6. router
    (void)hipMemsetAsync(cnt, 0, NE * sizeof(int), stream);
    router_kernel<<<SEQ, 256, 0, stream>>>(x, gate_w, gate_bias, toklist, tokw, cnt);
    prefix_kernel<<<1, 64, 0, stream>>>(cnt, base);
    // 7. MoE (BM=256, BN=32, BK=64, depth-1 prefetch — R14 proven)
    moe_gemm1_mfma<<<dim3(DFF / 32, SEQ / 256, NE), 256, 0, stream>>>(xbuf, gate_up_w, toklist, cnt, base, act);
    moe_gemm2_mfma<<<dim3(H_DIM / 32, SEQ / 256, NE), 256, 0, stream>>>(act, down_w, toklist, tokw, cnt, base, out);
}

// Round 22
// 379.970 us; speedup vs baseline: 1.0457x; 1.0033x over previous
//
#include <hip/hip_runtime.h>
#include <hip/hip_bf16.h>
#include <math.h>

#define H_DIM   2048
#define NH      16
#define NKV     4
#define HD      128
#define NE      16
#define TOPK    4
#define DFF     1024
#define NG      4
#define SEQ     1024
#define QKV_N   3072          // (NH + 2*NKV)*HD
#define EPS_RMS 1e-6f
#define THETA   1000000.0f

typedef __attribute__((ext_vector_type(8))) short bf16x8;
typedef __attribute__((ext_vector_type(4))) short s16x4;
typedef __attribute__((ext_vector_type(4))) float f32x4;

__device__ inline unsigned short f2bf(float x) {
    unsigned u = __builtin_bit_cast(unsigned, x);
    unsigned r = (u + 0x7FFFu + ((u >> 16) & 1u)) >> 16;
    return (unsigned short)r;
}

// pack two floats -> u32 of 2 bf16 (lo, hi); lowers to v_cvt_pk_bf16_f32
__device__ inline unsigned pk2bf(float lo, float hi) {
    __hip_bfloat162 h = __float22bfloat162_rn(float2{lo, hi});
    unsigned r;
    __builtin_memcpy(&r, &h, 4);
    return r;
}

// ---------------------------------------------------------------- weight transpose + bf16 convert (qkv_w only)
__global__ __launch_bounds__(256) void w2bfT(const float* __restrict__ in,
                                             unsigned short* __restrict__ out,
                                             int K, int N) {
    const float* src = in + (size_t)blockIdx.z * K * N;
    unsigned short* dst = out + (size_t)blockIdx.z * K * N;
    int n0 = blockIdx.x * 64, k0 = blockIdx.y * 64;
    __shared__ unsigned short tile[64][66];
    int tid = threadIdx.x, c = tid & 63, r4 = tid >> 6;
    #pragma unroll
    for (int rep = 0; rep < 16; rep++) {
        int r = rep * 4 + r4;
        tile[r][c] = f2bf(src[(size_t)(k0 + r) * N + n0 + c]);
    }
    __syncthreads();
    #pragma unroll
    for (int rep = 0; rep < 16; rep++) {
        int r = rep * 4 + r4;
        dst[(size_t)(n0 + r) * K + k0 + c] = tile[c][r];
    }
}

// ---------------------------------------------------------------- RMSNorm (f32 in, optional f32 + bf16 out)
__global__ __launch_bounds__(256) void rmsnorm_dual(const float* __restrict__ in,
                                                    const float* __restrict__ w,
                                                    float* __restrict__ outf,
                                                    unsigned short* __restrict__ outb) {
    int t = blockIdx.x;
    const float* xt = in + (size_t)t * H_DIM;
    float ss = 0.f;
    for (int d = threadIdx.x * 4; d < H_DIM; d += 1024) {
        float4 v = *reinterpret_cast<const float4*>(xt + d);
        ss += v.x * v.x + v.y * v.y + v.z * v.z + v.w * v.w;
    }
    for (int off = 1; off < 64; off <<= 1) ss += __shfl_xor(ss, off);
    __shared__ float red[4];
    __shared__ float srms;
    if ((threadIdx.x & 63) == 0) red[threadIdx.x >> 6] = ss;
    __syncthreads();
    if (threadIdx.x == 0)
        srms = rsqrtf((red[0] + red[1] + red[2] + red[3]) * (1.f / H_DIM) + EPS_RMS);
    __syncthreads();
    float r = srms;
    for (int d = threadIdx.x * 4; d < H_DIM; d += 1024) {
        float4 v  = *reinterpret_cast<const float4*>(xt + d);
        float4 wv = *reinterpret_cast<const float4*>(w + d);
        float4 ov;
        ov.x = v.x * r * wv.x; ov.y = v.y * r * wv.y;
        ov.z = v.z * r * wv.z; ov.w = v.w * r * wv.w;
        if (outf) *reinterpret_cast<float4*>(outf + (size_t)t * H_DIM + d) = ov;
        if (outb) {
            s16x4 bv = (s16x4){(short)f2bf(ov.x), (short)f2bf(ov.y),
                               (short)f2bf(ov.z), (short)f2bf(ov.w)};
            *reinterpret_cast<s16x4*>(outb + (size_t)t * H_DIM + d) = bv;
        }
    }
}

// ---------------------------------------------------------------- qkv GEMM (Bt bf16) fused RoPE + pack
// BM=64 (2 waves x 32 rows), BN=128 (=1 head), BK=64. 128 threads. grid (24, SEQ/64)
__global__ __launch_bounds__(128) void gemm_qkv_rope(const unsigned short* __restrict__ A,
                                                     const unsigned short* __restrict__ Bt,
                                                     const int* __restrict__ positions,
                                                     unsigned short* __restrict__ Qb,
                                                     unsigned short* __restrict__ Kb,
                                                     unsigned short* __restrict__ Vt) {
    __shared__ unsigned short As[8][66][8];    // [kg][row][k&7], +2 row pad
    __shared__ unsigned short Bs[8][130][8];
    int xb = blockIdx.x;                       // 0..23: 0-15 Q heads, 16-19 K, 20-23 V
    int row0 = blockIdx.y * 64, col0 = xb * 128;
    int t = threadIdx.x;
    int w = t >> 6, lane = t & 63, lo = lane & 15, g = lane >> 4;
    int wr = w * 32;
    f32x4 acc[2][8];
    #pragma unroll
    for (int mi = 0; mi < 2; mi++)
        #pragma unroll
        for (int ni = 0; ni < 8; ni++) acc[mi][ni] = (f32x4){0.f, 0.f, 0.f, 0.f};
    int arow8 = t >> 3, ac = t & 7;            // 16 rows per pass, 8 lanes/row
    size_t aoff[4], boff[8];
    #pragma unroll
    for (int rep = 0; rep < 4; rep++)
        aoff[rep] = (size_t)(row0 + rep * 16 + arow8) * H_DIM + ac * 8;
    #pragma unroll
    for (int rep = 0; rep < 8; rep++)
        boff[rep] = (size_t)(col0 + rep * 16 + arow8) * H_DIM + ac * 8;
    bf16x8 aR[4], bR[8];
    #pragma unroll
    for (int rep = 0; rep < 4; rep++) aR[rep] = *(const bf16x8*)(A + aoff[rep]);
    #pragma unroll
    for (int rep = 0; rep < 8; rep++) bR[rep] = *(const bf16x8*)(Bt + boff[rep]);
    for (int k0 = 0; k0 < H_DIM; k0 += 64) {
        #pragma unroll
        for (int rep = 0; rep < 4; rep++)
            *(bf16x8*)As[ac][rep * 16 + arow8] = aR[rep];
        #pragma unroll
        for (int rep = 0; rep < 8; rep++)
            *(bf16x8*)Bs[ac][rep * 16 + arow8] = bR[rep];
        int kn = k0 + 64;
        if (kn < H_DIM) {
            #pragma unroll
            for (int rep = 0; rep < 4; rep++) aR[rep] = *(const bf16x8*)(A + aoff[rep] + kn);
            #pragma unroll
            for (int rep = 0; rep < 8; rep++) bR[rep] = *(const bf16x8*)(Bt + boff[rep] + kn);
        }
        __syncthreads();
        #pragma unroll
        for (int kh = 0; kh < 2; kh++) {
            bf16x8 af[2], bfr[8];
            #pragma unroll
            for (int mi = 0; mi < 2; mi++) af[mi] = *(const bf16x8*)As[kh * 4 + g][wr + mi * 16 + lo];
            #pragma unroll
            for (int ni = 0; ni < 8; ni++) bfr[ni] = *(const bf16x8*)Bs[kh * 4 + g][ni * 16 + lo];
            #pragma unroll
            for (int mi = 0; mi < 2; mi++)
                #pragma unroll
                for (int ni = 0; ni < 8; ni++)
                    acc[mi][ni] = __builtin_amdgcn_mfma_f32_16x16x32_bf16(af[mi], bfr[ni], acc[mi][ni], 0, 0, 0);
        }
        __syncthreads();
    }
    if (xb < NH + NKV) {
        bool isQ = (xb < NH);
        unsigned short* dst = isQ ? (Qb + (size_t)xb * SEQ * HD)
                                  : (Kb + (size_t)(xb - NH) * SEQ * HD);
        float qs = isQ ? 0.08838834764831845f : 1.0f;
        float invf[4];
        #pragma unroll
        for (int ni = 0; ni < 4; ni++)
            invf[ni] = __powf(THETA, -(float)(ni * 16 + lo) * (1.0f / 64.0f));
        #pragma unroll
        for (int mi = 0; mi < 2; mi++)
            #pragma unroll
            for (int r = 0; r < 4; r++) {
                int tok = row0 + wr + mi * 16 + g * 4 + r;
                float pos = (float)positions[tok];
                #pragma unroll
                for (int ni = 0; ni < 4; ni++) {
                    float s, c;
                    __sincosf(pos * invf[ni], &s, &c);
                    float x1 = acc[mi][ni][r], x2 = acc[mi][ni + 4][r];
                    int d = ni * 16 + lo;
                    dst[(size_t)tok * HD + d]      = f2bf((x1 * c - x2 * s) * qs);
                    dst[(size_t)tok * HD + d + 64] = f2bf((x2 * c + x1 * s) * qs);
                }
            }
    } else {
        int kvh = xb - (NH + NKV);
        #pragma unroll
        for (int mi = 0; mi < 2; mi++)
            #pragma unroll
            for (int ni = 0; ni < 8; ni++) {
                int tok0 = row0 + wr + mi * 16 + g * 4;
                int d = ni * 16 + lo;
                ushort4 v4;
                v4.x = f2bf(acc[mi][ni][0]);
                v4.y = f2bf(acc[mi][ni][1]);
                v4.z = f2bf(acc[mi][ni][2]);
                v4.w = f2bf(acc[mi][ni][3]);
                *reinterpret_cast<ushort4*>(Vt + ((size_t)kvh * HD + d) * SEQ + tok0) = v4;
            }
    }
}

// ---------------------------------------------------------------- o-proj GEMM + residual, fused f32 weight staging
// B = o_w f32 [K][N]. BM=128, BN=64, BK=64. 256 threads. grid (N/64, M/128).
// B staging: rp=t>>4 (k row-pairs {2rp,2rp+1,2rp+32,2rp+33}), nq=t&15 (cols nq*4..+3) — moe_gemm2 pattern.
__global__ __launch_bounds__(256) void gemm_oproj(const unsigned short* __restrict__ A,
                                                  const float* __restrict__ B,
                                                  float* __restrict__ C,
                                                  float* __restrict__ C2,
                                                  const float* __restrict__ R,
                                                  int M, int N, int K) {
    __shared__ unsigned short As[8][130][8];
    __shared__ unsigned short Bs[8][66][8];
    int row0 = blockIdx.y * 128, col0 = blockIdx.x * 64;
    int t = threadIdx.x;
    int w = t >> 6, lane = t & 63, lo = lane & 15, g = lane >> 4;
    int wr = (w >> 1) * 64, wc = (w & 1) * 32;
    f32x4 acc[4][2];
    #pragma unroll
    for (int mi = 0; mi < 4; mi++)
        #pragma unroll
        for (int ni = 0; ni < 2; ni++) acc[mi][ni] = (f32x4){0.f, 0.f, 0.f, 0.f};
    int arow8 = t >> 3, ac = t & 7;
    size_t aoff[4];
    #pragma unroll
    for (int rep = 0; rep < 4; rep++)
        aoff[rep] = (size_t)(row0 + rep * 32 + arow8) * K + ac * 8;
    int rp = t >> 4, nq = t & 15;
    int kgB = rp >> 2, wq = (rp & 3) * 2;
    const float* pB0 = B + (size_t)(2 * rp) * N + col0 + nq * 4;
    bf16x8 aR[4];
    #pragma unroll
    for (int rep = 0; rep < 4; rep++) aR[rep] = *(const bf16x8*)(A + aoff[rep]);
    f32x4 bR0 = *(const f32x4*)pB0;
    f32x4 bR1 = *(const f32x4*)(pB0 + N);
    f32x4 bR2 = *(const f32x4*)(pB0 + (size_t)32 * N);
    f32x4 bR3 = *(const f32x4*)(pB0 + (size_t)33 * N);
    for (int k0 = 0; k0 < K; k0 += 64) {
        #pragma unroll
        for (int rep = 0; rep < 4; rep++)
            *(bf16x8*)As[ac][rep * 32 + arow8] = aR[rep];
        #pragma unroll
        for (int j = 0; j < 4; j++) {
            *(unsigned*)&Bs[kgB][nq * 4 + j][wq]     = pk2bf(bR0[j], bR1[j]);
            *(unsigned*)&Bs[kgB + 4][nq * 4 + j][wq] = pk2bf(bR2[j], bR3[j]);
        }
        int kn = k0 + 64;
        if (kn < K) {
            #pragma unroll
            for (int rep = 0; rep < 4; rep++) aR[rep] = *(const bf16x8*)(A + aoff[rep] + kn);
            const float* pB = pB0 + (size_t)kn * N;
            bR0 = *(const f32x4*)pB;
            bR1 = *(const f32x4*)(pB + N);
            bR2 = *(const f32x4*)(pB + (size_t)32 * N);
            bR3 = *(const f32x4*)(pB + (size_t)33 * N);
        }
        __syncthreads();
        #pragma unroll
        for (int kh = 0; kh < 2; kh++) {
            bf16x8 af[4], bfr[2];
            #pragma unroll
            for (int mi = 0; mi < 4; mi++) af[mi] = *(const bf16x8*)As[kh * 4 + g][wr + mi * 16 + lo];
            #pragma unroll
            for (int ni = 0; ni < 2; ni++) bfr[ni] = *(const bf16x8*)Bs[kh * 4 + g][wc + ni * 16 + lo];
            #pragma unroll
            for (int mi = 0; mi < 4; mi++)
                #pragma unroll
                for (int ni = 0; ni < 2; ni++)
                    acc[mi][ni] = __builtin_amdgcn_mfma_f32_16x16x32_bf16(af[mi], bfr[ni], acc[mi][ni], 0, 0, 0);
        }
        __syncthreads();
    }
    #pragma unroll
    for (int mi = 0; mi < 4; mi++)
        #pragma unroll
        for (int ni = 0; ni < 2; ni++)
            #pragma unroll
            for (int r = 0; r < 4; r++) {
                int row = row0 + wr + mi * 16 + g * 4 + r;
                int col = col0 + wc + ni * 16 + lo;
                size_t idx = (size_t)row * N + col;
                float v = acc[mi][ni][r];
                if (R)  v += R[idx];
                C[idx] = v;
                if (C2) C2[idx] = v;
            }
}

// ---------------------------------------------------------------- flash attention, 4 waves / block:
// (mirrored q-pair) x (kv-half split) -> 8 waves/CU, halved critical path.
__global__ __launch_bounds__(256) void attn_mfma(const unsigned short* __restrict__ Qb,
                                                 const unsigned short* __restrict__ Kb,
                                                 const unsigned short* __restrict__ Vt,
                                                 unsigned short* __restrict__ ob) {
    int bx = blockIdx.x;
    int h  = blockIdx.y;
    int kvh = h >> 2;
    int tid = threadIdx.x;
    int wid = tid >> 6;
    int qsel = wid >> 1, khalf = wid & 1;
    int qt = qsel ? (SEQ / 16 - 1 - bx) : bx;
    int q0 = qt * 16;
    int l = tid & 63;
    int lo = l & 15, g = l >> 4;

    __shared__ alignas(16) unsigned short pbuf[4][16][40];
    __shared__ float obuf[2][16][128];
    __shared__ float mbuf[2][16], lbuf[2][16];

    bf16x8 qf[4];
    const unsigned short* qp = Qb + ((size_t)h * SEQ + q0 + lo) * HD + g * 8;
    #pragma unroll
    for (int ks = 0; ks < 4; ks++)
        qf[ks] = *(const bf16x8*)(qp + ks * 32);

    f32x4 accO[8];
    #pragma unroll
    for (int nd = 0; nd < 8; nd++) accO[nd] = (f32x4){0.f, 0.f, 0.f, 0.f};
    float mrun[4], lrun[4];
    #pragma unroll
    for (int r = 0; r < 4; r++) { mrun[r] = -INFINITY; lrun[r] = 0.f; }

    int nc = (q0 + 16 + 31) / 32;
    int ncH = (nc + 1) >> 1;
    int cbeg = khalf ? ncH : 0;
    int cend = khalf ? nc : ncH;
    for (int ch = cbeg; ch < cend; ch++) {
        int kv0 = ch * 32;
        f32x4 accS[2];
        accS[0] = (f32x4){0.f, 0.f, 0.f, 0.f};
        accS[1] = (f32x4){0.f, 0.f, 0.f, 0.f};
        const unsigned short* kp = Kb + ((size_t)kvh * SEQ + kv0 + lo) * HD + g * 8;
        #pragma unroll
        for (int n = 0; n < 2; n++) {
            const unsigned short* kpn = kp + (size_t)n * 16 * HD;
            #pragma unroll
            for (int ks = 0; ks < 4; ks++) {
                bf16x8 kf = *(const bf16x8*)(kpn + ks * 32);
                accS[n] = __builtin_amdgcn_mfma_f32_16x16x32_bf16(qf[ks], kf, accS[n], 0, 0, 0);
            }
        }
        if (ch == nc - 1) {
            #pragma unroll
            for (int n = 0; n < 2; n++)
                #pragma unroll
                for (int r = 0; r < 4; r++) {
                    int kv = kv0 + n * 16 + lo;
                    int q  = q0 + g * 4 + r;
                    if (kv > q) accS[n][r] = -1e30f;
                }
        }
        float mt[4], fac[4];
        #pragma unroll
        for (int r = 0; r < 4; r++) {
            float m = fmaxf(accS[0][r], accS[1][r]);
            #pragma unroll
            for (int off = 1; off < 16; off <<= 1) m = fmaxf(m, __shfl_xor(m, off));
            mt[r] = fmaxf(mrun[r], m);
            fac[r] = __expf(mrun[r] - mt[r]);
        }
        float psum[4] = {0.f, 0.f, 0.f, 0.f};
        #pragma unroll
        for (int n = 0; n < 2; n++)
            #pragma unroll
            for (int r = 0; r < 4; r++) {
                float p = __expf(accS[n][r] - mt[r]);
                psum[r] += p;
                pbuf[wid][g * 4 + r][n * 16 + lo] = f2bf(p);
            }
        #pragma unroll
        for (int r = 0; r < 4; r++) {
            float s = psum[r];
            #pragma unroll
            for (int off = 1; off < 16; off <<= 1) s += __shfl_xor(s, off);
            lrun[r] = lrun[r] * fac[r] + s;
            mrun[r] = mt[r];
        }
        #pragma unroll
        for (int nd = 0; nd < 8; nd++)
            #pragma unroll
            for (int r = 0; r < 4; r++) accO[nd][r] *= fac[r];
        __builtin_amdgcn_sched_barrier(0);
        bf16x8 pf = *(const bf16x8*)(&pbuf[wid][lo][g * 8]);
        const unsigned short* vp = Vt + ((size_t)kvh * HD + lo) * SEQ + kv0 + g * 8;
        #pragma unroll
        for (int nd = 0; nd < 8; nd++) {
            bf16x8 vf = *(const bf16x8*)(vp + (size_t)nd * 16 * SEQ);
            accO[nd] = __builtin_amdgcn_mfma_f32_16x16x32_bf16(pf, vf, accO[nd], 0, 0, 0);
        }
        __builtin_amdgcn_sched_barrier(0);
    }
    // kv-half merge: wave khalf=1 publishes partials; khalf=0 merges + writes out
    if (khalf) {
        #pragma unroll
        for (int r = 0; r < 4; r++) {
            if (lo == 0) {
                mbuf[qsel][g * 4 + r] = mrun[r];
                lbuf[qsel][g * 4 + r] = lrun[r];
            }
            #pragma unroll
            for (int nd = 0; nd < 8; nd++)
                obuf[qsel][g * 4 + r][nd * 16 + lo] = accO[nd][r];
        }
    }
    __syncthreads();
    if (!khalf) {
        #pragma unroll
        for (int r = 0; r < 4; r++) {
            int row = g * 4 + r;
            float m1 = mbuf[qsel][row], l1 = lbuf[qsel][row];
            float m0 = mrun[r], l0 = lrun[r];
            float m = fmaxf(m0, m1);
            float f0 = (l0 > 0.f) ? __expf(m0 - m) : 0.f;
            float f1 = (l1 > 0.f) ? __expf(m1 - m) : 0.f;
            float linv = 1.f / (l0 * f0 + l1 * f1);
            #pragma unroll
            for (int nd = 0; nd < 8; nd++) {
                float v = (accO[nd][r] * f0 + obuf[qsel][row][nd * 16 + lo] * f1) * linv;
                ob[(size_t)(q0 + row) * H_DIM + h * HD + nd * 16 + lo] = f2bf(v);
            }
        }
    }
}

// ---------------------------------------------------------------- router (wave-parallel: 4 waves x 4 experts)
__global__ __launch_bounds__(256) void router_kernel(const float* __restrict__ x,
                                                     const float* __restrict__ gate_w,
                                                     const float* __restrict__ gate_bias,
                                                     int* __restrict__ toklist,
                                                     float* __restrict__ tokw,
                                                     int* __restrict__ cnt) {
    int t = blockIdx.x;
    const float* xt = x + (size_t)t * H_DIM;
    __shared__ float logits[NE];
    int wid = threadIdx.x >> 6, lane = threadIdx.x & 63;
    #pragma unroll
    for (int i = 0; i < 4; i++) {
        int e = wid * 4 + i;
        const float* gw = gate_w + (size_t)e * H_DIM;
        float p = 0.f;
        for (int d = lane * 4; d < H_DIM; d += 256) {
            float4 xv = *reinterpret_cast<const float4*>(xt + d);
            float4 wv = *reinterpret_cast<const float4*>(gw + d);
            p += xv.x * wv.x + xv.y * wv.y + xv.z * wv.z + xv.w * wv.w;
        }
        #pragma unroll
        for (int off = 1; off < 64; off <<= 1) p += __shfl_xor(p, off);
        if (lane == 0) logits[e] = p;
    }
    __syncthreads();
    if (threadIdx.x == 0) {
        float sig[NE], sb[NE];
        for (int e = 0; e < NE; e++) {
            sig[e] = 1.f / (1.f + expf(-logits[e]));
            sb[e] = sig[e] + gate_bias[e];
        }
        float gs[NG];
        for (int g = 0; g < NG; g++) {
            float m1 = -1e30f, m2 = -1e30f;
            for (int i = 0; i < 4; i++) {
                float v = sb[g * 4 + i];
                if (v > m1) { m2 = m1; m1 = v; } else if (v > m2) m2 = v;
            }
            gs[g] = m1 + m2;
        }
        int g1 = 0;
        for (int g = 1; g < NG; g++) if (gs[g] > gs[g1]) g1 = g;
        int g2 = -1;
        for (int g = 0; g < NG; g++) {
            if (g == g1) continue;
            if (g2 < 0 || gs[g] > gs[g2]) g2 = g;
        }
        bool allowed[NE], used[NE];
        for (int e = 0; e < NE; e++) { int g = e >> 2; allowed[e] = (g == g1 || g == g2); used[e] = false; }
        int sel[TOPK]; float wsel[TOPK]; float wsum = 0.f;
        for (int k = 0; k < TOPK; k++) {
            int best = -1; float bv = -1e30f;
            for (int e = 0; e < NE; e++) {
                if (!allowed[e] || used[e]) continue;
                if (best < 0 || sb[e] > bv) { best = e; bv = sb[e]; }
            }
            used[best] = true; sel[k] = best; wsel[k] = sig[best]; wsum += sig[best];
        }
        float invs = 1.f / (wsum + 1e-20f);
        for (int k = 0; k < TOPK; k++) {
            int e = sel[k];
            int slot = atomicAdd(&cnt[e], 1);
            toklist[e * SEQ + slot] = t;
            tokw[e * SEQ + slot] = wsel[k] * invs;
        }
    }
}

// ---------------------------------------------------------------- MoE GEMM1: act = silu(x@G)*(x@U)
// BM=256, BN=32 (G and U each), BK=64, depth-1 prefetch. Inline expert-base prefix.
// grid (DFF/32, ceil(SEQ/256), NE)
__global__ __launch_bounds__(256, 2) void moe_gemm1_mfma(const unsigned short* __restrict__ xb,
                                                         const float* __restrict__ gup,
                                                         const int* __restrict__ toklist,
                                                         const int* __restrict__ cnt,
                                                         unsigned short* __restrict__ act) {
    int e = blockIdx.z;
    int ce = cnt[e];
    int t0 = blockIdx.y * 256;
    if (t0 >= ce) return;
    int f0 = blockIdx.x * 32;
    __shared__ unsigned short As[8][258][8];   // [kg][row][k&7]
    __shared__ unsigned short BsG[8][33][8];
    __shared__ unsigned short BsU[8][33][8];
    __shared__ int toks[256];
    int t = threadIdx.x;
    { int s = t0 + t; toks[t] = toklist[e * SEQ + (s < ce ? s : 0)]; }
    __syncthreads();
    int w = t >> 6, lane = t & 63, lo = lane & 15, g = lane >> 4;
    int wrb = w * 64;
    f32x4 accG[4][2], accU[4][2];
    #pragma unroll
    for (int mi = 0; mi < 4; mi++)
        #pragma unroll
        for (int ni = 0; ni < 2; ni++) {
            accG[mi][ni] = (f32x4){0.f, 0.f, 0.f, 0.f};
            accU[mi][ni] = (f32x4){0.f, 0.f, 0.f, 0.f};
        }
    // A staging: 8 lanes per row (128B line), 32 rows per pass, 8 passes
    int arow8 = t >> 3, ac = t & 7;
    size_t abase[8];
    #pragma unroll
    for (int rep = 0; rep < 8; rep++)
        abase[rep] = (size_t)toks[rep * 32 + arow8] * H_DIM + ac * 8;
    // B staging: t<128 -> G, t>=128 -> U; rows {2rp,2rp+1,2rp+32,2rp+33}, cols nq*4..+3
    int half = t >> 7, tt = t & 127;
    int rp = tt >> 3, nq = tt & 7;
    int kgB = rp >> 2, wq = (rp & 3) * 2;
    unsigned short (*Bsel)[33][8] = half ? BsU : BsG;
    const float* W = gup + (size_t)e * H_DIM * (2 * DFF);
    const float* pB0 = W + (size_t)(2 * rp) * (2 * DFF) + half * DFF + f0 + nq * 4;
    // prologue
    bf16x8 aR[8];
    #pragma unroll
    for (int rep = 0; rep < 8; rep++) aR[rep] = *(const bf16x8*)(xb + abase[rep]);
    f32x4 bR0 = *(const f32x4*)pB0;
    f32x4 bR1 = *(const f32x4*)(pB0 + 2 * DFF);
    f32x4 bR2 = *(const f32x4*)(pB0 + (size_t)32 * 2 * DFF);
    f32x4 bR3 = *(const f32x4*)(pB0 + (size_t)33 * 2 * DFF);
    for (int k0 = 0; k0 < H_DIM; k0 += 64) {
        #pragma unroll
        for (int rep = 0; rep < 8; rep++)
            *(bf16x8*)As[ac][rep * 32 + arow8] = aR[rep];
        #pragma unroll
        for (int j = 0; j < 4; j++) {
            *(unsigned*)&Bsel[kgB][nq * 4 + j][wq]     = pk2bf(bR0[j], bR1[j]);
            *(unsigned*)&Bsel[kgB + 4][nq * 4 + j][wq] = pk2bf(bR2[j], bR3[j]);
        }
        int kn = k0 + 64;
        if (kn < H_DIM) {
            #pragma unroll
            for (int rep = 0; rep < 8; rep++)
                aR[rep] = *(const bf16x8*)(xb + abase[rep] + kn);
            const float* pB = pB0 + (size_t)kn * (2 * DFF);
            bR0 = *(const f32x4*)pB;
            bR1 = *(const f32x4*)(pB + 2 * DFF);
            bR2 = *(const f32x4*)(pB + (size_t)32 * 2 * DFF);
            bR3 = *(const f32x4*)(pB + (size_t)33 * 2 * DFF);
        }
        __syncthreads();
        #pragma unroll
        for (int kh = 0; kh < 2; kh++) {
            bf16x8 af[4], bg[2], bu[2];
            #pragma unroll
            for (int mi = 0; mi < 4; mi++) af[mi] = *(const bf16x8*)As[kh * 4 + g][wrb + mi * 16 + lo];
            #pragma unroll
            for (int ni = 0; ni < 2; ni++) {
                bg[ni] = *(const bf16x8*)BsG[kh * 4 + g][ni * 16 + lo];
                bu[ni] = *(const bf16x8*)BsU[kh * 4 + g][ni * 16 + lo];
            }
            #pragma unroll
            for (int mi = 0; mi < 4; mi++)
                #pragma unroll
                for (int ni = 0; ni < 2; ni++) {
                    accG[mi][ni] = __builtin_amdgcn_mfma_f32_16x16x32_bf16(af[mi], bg[ni], accG[mi][ni], 0, 0, 0);
                    accU[mi][ni] = __builtin_amdgcn_mfma_f32_16x16x32_bf16(af[mi], bu[ni], accU[mi][ni], 0, 0, 0);
                }
        }
        __syncthreads();
    }
    int b = 0;
    for (int ee = 0; ee < e; ee++) b += cnt[ee];
    #pragma unroll
    for (int mi = 0; mi < 4; mi++)
        #pragma unroll
        for (int ni = 0; ni < 2; ni++)
            #pragma unroll
            for (int r = 0; r < 4; r++) {
                int slot = t0 + wrb + mi * 16 + g * 4 + r;
                if (slot < ce) {
                    float gv = accG[mi][ni][r], uv = accU[mi][ni][r];
                    float a = (gv / (1.f + __expf(-gv))) * uv;
                    act[(size_t)(b + slot) * DFF + f0 + ni * 16 + lo] = f2bf(a);
                }
            }
}

// ---------------------------------------------------------------- MoE GEMM2: out += w * (act @ down)
// BM=256, BN=32, BK=64, depth-1 prefetch. Inline expert-base prefix. grid (H_DIM/32, ceil(SEQ/256), NE)
__global__ __launch_bounds__(256, 4) void moe_gemm2_mfma(const unsigned short* __restrict__ act,
                                                         const float* __restrict__ down,
                                                         const int* __restrict__ toklist,
                                                         const float* __restrict__ tokw,
                                                         const int* __restrict__ cnt,
                                                         float* __restrict__ out) {
    int e = blockIdx.z;
    int ce = cnt[e];
    int t0 = blockIdx.y * 256;
    if (t0 >= ce) return;
    int c0 = blockIdx.x * 32;
    __shared__ unsigned short As[8][258][8];
    __shared__ unsigned short Bs[8][33][8];
    int t = threadIdx.x;
    int w = t >> 6, lane = t & 63, lo = lane & 15, g = lane >> 4;
    int wrb = w * 64;
    int b = 0;
    for (int ee = 0; ee < e; ee++) b += cnt[ee];
    f32x4 acc[4][2];
    #pragma unroll
    for (int mi = 0; mi < 4; mi++)
        #pragma unroll
        for (int ni = 0; ni < 2; ni++) acc[mi][ni] = (f32x4){0.f, 0.f, 0.f, 0.f};
    int arow8 = t >> 3, ac = t & 7;
    size_t abase[8];
    #pragma unroll
    for (int rep = 0; rep < 8; rep++) {
        int slot = t0 + rep * 32 + arow8;
        abase[rep] = (size_t)(b + (slot < ce ? slot : t0)) * DFF + ac * 8;
    }
    int tt = t & 127;
    int rp = tt >> 3, nq = tt & 7;
    int kgB = rp >> 2, wq = (rp & 3) * 2;
    const float* pB0 = down + (size_t)e * DFF * H_DIM + (size_t)(2 * rp) * H_DIM + c0 + nq * 4;
    bool stageB = (t < 128);
    // prologue
    bf16x8 aR[8];
    #pragma unroll
    for (int rep = 0; rep < 8; rep++) aR[rep] = *(const bf16x8*)(act + abase[rep]);
    f32x4 bR0 = (f32x4){0.f,0.f,0.f,0.f}, bR1 = bR0, bR2 = bR0, bR3 = bR0;
    if (stageB) {
        bR0 = *(const f32x4*)pB0;
        bR1 = *(const f32x4*)(pB0 + H_DIM);
        bR2 = *(const f32x4*)(pB0 + (size_t)32 * H_DIM);
        bR3 = *(const f32x4*)(pB0 + (size_t)33 * H_DIM);
    }
    for (int k0 = 0; k0 < DFF; k0 += 64) {
        #pragma unroll
        for (int rep = 0; rep < 8; rep++)
            *(bf16x8*)As[ac][rep * 32 + arow8] = aR[rep];
        if (stageB) {
            #pragma unroll
            for (int j = 0; j < 4; j++) {
                *(unsigned*)&Bs[kgB][nq * 4 + j][wq]     = pk2bf(bR0[j], bR1[j]);
                *(unsigned*)&Bs[kgB + 4][nq * 4 + j][wq] = pk2bf(bR2[j], bR3[j]);
            }
        }
        int kn = k0 + 64;
        if (kn < DFF) {
            #pragma unroll
            for (int rep = 0; rep < 8; rep++)
                aR[rep] = *(const bf16x8*)(act + abase[rep] + kn);
            if (stageB) {
                const float* pB = pB0 + (size_t)kn * H_DIM;
                bR0 = *(const f32x4*)pB;
                bR1 = *(const f32x4*)(pB + H_DIM);
                bR2 = *(const f32x4*)(pB + (size_t)32 * H_DIM);
                bR3 = *(const f32x4*)(pB + (size_t)33 * H_DIM);
            }
        }
        __syncthreads();
        #pragma unroll
        for (int kh = 0; kh < 2; kh++) {
            bf16x8 af[4], bfr[2];
            #pragma unroll
            for (int mi = 0; mi < 4; mi++) af[mi] = *(const bf16x8*)As[kh * 4 + g][wrb + mi * 16 + lo];
            #pragma unroll
            for (int ni = 0; ni < 2; ni++) bfr[ni] = *(const bf16x8*)Bs[kh * 4 + g][ni * 16 + lo];
            #pragma unroll
            for (int mi = 0; mi < 4; mi++)
                #pragma unroll
                for (int ni = 0; ni < 2; ni++)
                    acc[mi][ni] = __builtin_amdgcn_mfma_f32_16x16x32_bf16(af[mi], bfr[ni], acc[mi][ni], 0, 0, 0);
        }
        __syncthreads();
    }
    #pragma unroll
    for (int mi = 0; mi < 4; mi++)
        #pragma unroll
        for (int r = 0; r < 4; r++) {
            int slot = t0 + wrb + mi * 16 + g * 4 + r;
            if (slot < ce) {
                int tok = toklist[e * SEQ + slot];
                float wt = tokw[e * SEQ + slot];
                #pragma unroll
                for (int ni = 0; ni < 2; ni++)
                    atomicAdd(&out[(size_t)tok * H_DIM + c0 + ni * 16 + lo],
                              wt * acc[mi][ni][r]);
            }
        }
}

// ---------------------------------------------------------------- launch
extern "C" void kernel_launch(void* const* d_in, const int* in_sizes, int n_in,
                              void* d_out, int out_size, void* d_ws, size_t ws_size,
                              hipStream_t stream) {
    const float* hidden     = (const float*)d_in[0];
    const int*   positions  = (const int*)d_in[1];
    const float* in_norm_w  = (const float*)d_in[2];
    const float* post_norm_w= (const float*)d_in[3];
    const float* qkv_w      = (const float*)d_in[4];
    const float* o_w        = (const float*)d_in[5];
    const float* gate_w     = (const float*)d_in[6];
    const float* gate_bias  = (const float*)d_in[7];
    const float* gate_up_w  = (const float*)d_in[8];
    const float* down_w     = (const float*)d_in[9];
    float* out = (float*)d_out;

    float* ws   = (float*)d_ws;
    float* h2   = ws;                                  // 1024*2048 f32
    float* x    = h2  + (size_t)SEQ * H_DIM;           // 1024*2048 f32
    float* tokw = x   + (size_t)SEQ * H_DIM;           // 16*1024
    int* toklist = (int*)(tokw + NE * SEQ);            // 16*1024
    int* cnt  = toklist + NE * SEQ;                    // 16
    int* base = cnt + NE;                              // 16 (reserved)
    unsigned short* hb = (unsigned short*)(base + NE); // 1024*2048 bf16
    unsigned short* ob = hb + (size_t)SEQ * H_DIM;     // 1024*2048
    unsigned short* xbuf = ob + (size_t)SEQ * H_DIM;   // 1024*2048
    unsigned short* act = xbuf + (size_t)SEQ * H_DIM;  // 4096*1024
    unsigned short* Qb = act + (size_t)4 * SEQ * DFF;  // 16*1024*128
    unsigned short* Kb = Qb + (size_t)NH * SEQ * HD;   // 4*1024*128
    unsigned short* Vt = Kb + (size_t)NKV * SEQ * HD;  // 4*128*1024
    unsigned short* qkvT = Vt + (size_t)NKV * HD * SEQ;        // 3072*2048

    // 0. qkv weight transpose only (o_w conversion is fused into gemm_oproj)
    w2bfT<<<dim3(QKV_N / 64, H_DIM / 64, 1), 256, 0, stream>>>(qkv_w, qkvT, H_DIM, QKV_N);

    // 1. pre-attention RMSNorm -> bf16
    rmsnorm_dual<<<SEQ, 256, 0, stream>>>(hidden, in_norm_w, nullptr, hb);
    // 2. qkv projection fused with RoPE + bf16/transpose pack
    gemm_qkv_rope<<<dim3(QKV_N / 128, SEQ / 64), 128, 0, stream>>>(hb, qkvT, positions, Qb, Kb, Vt);
    // 3. flash attention (bf16 MFMA), mirrored q-pair x kv-half split -> ob bf16
    attn_mfma<<<dim3(SEQ / 32, NH), 256, 0, stream>>>(Qb, Kb, Vt, ob);
    // 4. o projection + residual (fused f32 weight staging) -> h2 and d_out
    gemm_oproj<<<dim3(H_DIM / 64, SEQ / 128), 256, 0, stream>>>(ob, o_w, h2, out, hidden,
                                                                SEQ, H_DIM, H_DIM);
    // 5. post-attention RMSNorm -> x (f32 for router) + xbuf (bf16 for MoE)
    rmsnorm_dual<<<SEQ, 256, 0, stream>>>(h2, post_norm_w, x, xbuf);
    // 6. router (expert bases computed inline in MoE kernels)
    (void)hipMemsetAsync(cnt, 0, NE * sizeof(int), stream);
    router_kernel<<<SEQ, 256, 0, stream>>>(x, gate_w, gate_bias, toklist, tokw, cnt);
    // 7. MoE (BM=256, BN=32, BK=64, depth-1 prefetch)
    moe_gemm1_mfma<<<dim3(DFF / 32, SEQ / 256, NE), 256, 0, stream>>>(xbuf, gate_up_w, toklist, cnt, act);
    moe_gemm2_mfma<<<dim3(H_DIM / 32, SEQ / 256, NE), 256, 0, stream>>>(act, down_w, toklist, tokw, cnt, out);
}